// Round 1
// baseline (709.252 us; speedup 1.0000x reference)
//
#include <hip/hip_runtime.h>
#include <math.h>
#include <stdint.h>

#define NBATCH 2
#define NC 80
#define CHN 256
#define HMM 128
#define HWN (HMM*HMM)
#define NCELL 3872
#define FLATN (NCELL*NC)
#define TOPN 500
#define MAXM 100
#define OUTH 512
#define OUTW 512
#define NBINS 1024
#define CANDCAP 4096
#define BM 64
#define BN 128
#define GNB (HWN/BN)   // 128 N-blocks per row

__device__ __forceinline__ float sigmoidf_(float x){ return 1.0f/(1.0f+expf(-x)); }

__device__ __forceinline__ void cell_decode(int cell, int& lvl, int& g, int& y, int& x){
  int off;
  if (cell < 1600)      { lvl=0; g=40; off=0; }
  else if (cell < 2896) { lvl=1; g=36; off=1600; }
  else if (cell < 3472) { lvl=2; g=24; off=2896; }
  else if (cell < 3728) { lvl=3; g=16; off=3472; }
  else                  { lvl=4; g=12; off=3728; }
  int r = cell - off; y = r / g; x = r - y*g;
}

template<int N, int NT>
__device__ __forceinline__ void bitonic_desc(uint64_t* key){
  int tid = threadIdx.x;
  for (int k = 2; k <= N; k <<= 1)
    for (int j = k >> 1; j > 0; j >>= 1) {
      __syncthreads();
      for (int e = tid; e < N; e += NT) {
        int l = e ^ j;
        if (l > e) {
          uint64_t a = key[e], c = key[l];
          bool up = ((e & k) == 0);
          if (up ? (a < c) : (a > c)) { key[e] = c; key[l] = a; }
        }
      }
    }
  __syncthreads();
}

__global__ void k0_init(uint32_t* hist, uint32_t* cnt){
  int t = blockIdx.x*blockDim.x + threadIdx.x;
  if (t < NBATCH*NBINS) hist[t] = 0;
  if (t < NBATCH) cnt[t] = 0;
}

__global__ void k1_scores(const float* __restrict__ c0, const float* __restrict__ c1,
                          const float* __restrict__ c2, const float* __restrict__ c3,
                          const float* __restrict__ c4,
                          float* __restrict__ scores, uint32_t* __restrict__ hist){
  int t = blockIdx.x*blockDim.x + threadIdx.x;
  if (t >= NBATCH*FLATN) return;
  int b = t / FLATN;
  int rem = t - b*FLATN;
  int cell = rem / NC;
  int c = rem - cell*NC;
  int lvl,g,y,x; cell_decode(cell,lvl,g,y,x);
  const float* cp = lvl==0?c0:lvl==1?c1:lvl==2?c2:lvl==3?c3:c4;
  const float* base = cp + (size_t)(b*NC + c)*g*g;
  float raw = base[y*g + x];
  float m = raw;
  if (y > 0)          m = fmaxf(m, base[(y-1)*g + x]);
  if (x > 0)          m = fmaxf(m, base[y*g + x-1]);
  if (y > 0 && x > 0) m = fmaxf(m, base[(y-1)*g + x-1]);
  float s = (raw == m) ? sigmoidf_(raw) : 0.0f;
  scores[t] = s;
  if (s > 0.1f) {
    int bin = (int)(s * 1024.0f); if (bin > NBINS-1) bin = NBINS-1;
    atomicAdd(&hist[b*NBINS + bin], 1u);
  }
}

__global__ void k2_cutoff(const uint32_t* __restrict__ hist, int* __restrict__ cutoff){
  int b = blockIdx.x;
  int acc = 0; int cut = 0;
  for (int d = NBINS-1; d >= 0; --d) {
    acc += (int)hist[b*NBINS+d];
    if (acc >= TOPN) { cut = d; break; }
  }
  cutoff[b] = cut;
}

__global__ void k3_gather(const float* __restrict__ scores, const int* __restrict__ cutoff,
                          uint32_t* __restrict__ cnt, float* __restrict__ cval, uint32_t* __restrict__ cidx){
  int t = blockIdx.x*blockDim.x + threadIdx.x;
  if (t >= NBATCH*FLATN) return;
  int b = t / FLATN; int idx = t - b*FLATN;
  float v = scores[t];
  if (v > 0.1f) {
    int bin = (int)(v * 1024.0f); if (bin > NBINS-1) bin = NBINS-1;
    if (bin >= cutoff[b]) {
      uint32_t p = atomicAdd(&cnt[b], 1u);
      if (p < CANDCAP) { cval[b*CANDCAP+p] = v; cidx[b*CANDCAP+p] = (uint32_t)idx; }
    }
  }
}

__global__ __launch_bounds__(1024) void k4_sort(const uint32_t* __restrict__ cnt,
        const float* __restrict__ cval, const uint32_t* __restrict__ cidx,
        float* __restrict__ vals, int* __restrict__ cellA, int* __restrict__ labelA){
  __shared__ uint64_t key[CANDCAP];
  int b = blockIdx.x; int tid = threadIdx.x;
  int n = (int)cnt[b]; if (n > CANDCAP) n = CANDCAP;
  for (int e = tid; e < CANDCAP; e += 1024) {
    uint64_t k = 0;
    if (e < n)
      k = ((uint64_t)__float_as_uint(cval[b*CANDCAP+e]) << 32) |
          (uint64_t)(0xFFFFFFFFu - cidx[b*CANDCAP+e]);
    key[e] = k;
  }
  bitonic_desc<CANDCAP,1024>(key);
  for (int r = tid; r < TOPN; r += 1024) {
    uint64_t k = key[r];
    if ((k >> 32) == 0) { vals[b*TOPN+r] = -1.0f; cellA[b*TOPN+r] = 0; labelA[b*TOPN+r] = 0; }
    else {
      uint32_t idx = 0xFFFFFFFFu - (uint32_t)(k & 0xFFFFFFFFu);
      vals[b*TOPN+r]   = __uint_as_float((uint32_t)(k >> 32));
      cellA[b*TOPN+r]  = (int)(idx / NC);
      labelA[b*TOPN+r] = (int)(idx % NC);
    }
  }
}

__global__ void k5_kmat(const float* __restrict__ k0p, const float* __restrict__ k1p,
                        const float* __restrict__ k2p, const float* __restrict__ k3p,
                        const float* __restrict__ k4p,
                        const int* __restrict__ cellA, float* __restrict__ Kmat){
  int t = blockIdx.x*blockDim.x + threadIdx.x;
  if (t >= NBATCH*TOPN*CHN) return;
  int b = t / (TOPN*CHN); int rem = t - b*(TOPN*CHN);
  int k = rem / CHN; int c = rem - k*CHN;
  int cell = cellA[b*TOPN + k];
  int lvl,g,y,x; cell_decode(cell,lvl,g,y,x);
  const float* kp = lvl==0?k0p:lvl==1?k1p:lvl==2?k2p:lvl==3?k3p:k4p;
  Kmat[t] = kp[((size_t)(b*CHN + c)*g + y)*g + x];
}

__global__ __launch_bounds__(256) void k6_gemm1(const float* __restrict__ Kmat, const float* __restrict__ mf,
        uint32_t* __restrict__ bits, float* __restrict__ psum, float* __restrict__ pseg){
  __shared__ float As[BM][33];
  __shared__ float4 Bs4[32][BN/4];
  __shared__ uint32_t bitsL[BM][BN/32];
  float* BsF = (float*)Bs4;
  int tid = threadIdx.x;
  int nb = blockIdx.x, mb = blockIdx.y, b = blockIdx.z;
  int row0 = mb*BM, col0 = nb*BN;
  int tx = tid & 15, ty = tid >> 4;
  for (int i = tid; i < BM*(BN/32); i += 256) ((uint32_t*)bitsL)[i] = 0;
  float acc[4][8];
  #pragma unroll
  for (int i=0;i<4;i++)
    #pragma unroll
    for(int j=0;j<8;j++) acc[i][j]=0.f;
  for (int k0 = 0; k0 < CHN; k0 += 32) {
    __syncthreads();
    #pragma unroll
    for (int i = 0; i < 8; ++i) {
      int e = i*256 + tid;
      int r = e >> 5, kk = e & 31;
      float v = 0.f;
      if (row0 + r < TOPN) v = Kmat[((size_t)b*TOPN + row0 + r)*CHN + k0 + kk];
      As[r][kk] = v;
    }
    #pragma unroll
    for (int i = 0; i < 16; ++i) {
      int e = i*256 + tid;
      int kk = e >> 7, col = e & 127;
      BsF[kk*BN + col] = mf[((size_t)b*CHN + k0 + kk)*HWN + col0 + col];
    }
    __syncthreads();
    #pragma unroll
    for (int kk = 0; kk < 32; ++kk) {
      float4 b0 = Bs4[kk][tx*2];
      float4 b1 = Bs4[kk][tx*2+1];
      #pragma unroll
      for (int i = 0; i < 4; ++i) {
        float a = As[ty*4+i][kk];
        acc[i][0] += a*b0.x; acc[i][1] += a*b0.y; acc[i][2] += a*b0.z; acc[i][3] += a*b0.w;
        acc[i][4] += a*b1.x; acc[i][5] += a*b1.y; acc[i][6] += a*b1.z; acc[i][7] += a*b1.w;
      }
    }
  }
  #pragma unroll
  for (int i = 0; i < 4; ++i) {
    int r = row0 + ty*4 + i;
    uint32_t mybits = 0; float seg = 0.f; int cc = 0;
    #pragma unroll
    for (int j = 0; j < 8; ++j) {
      float s = sigmoidf_(acc[i][j]);
      if (s > 0.5f) { mybits |= (1u << j); seg += s; cc++; }
    }
    if (r < TOPN) atomicOr(&bitsL[ty*4+i][tx>>2], mybits << ((tx&3)*8));
    #pragma unroll
    for (int d = 1; d < 16; d <<= 1) {
      seg += __shfl_xor(seg, d);
      cc  += __shfl_xor(cc, d);
    }
    if (tx == 0 && r < TOPN) {
      psum[((size_t)b*TOPN + r)*GNB + nb] = (float)cc;
      pseg[((size_t)b*TOPN + r)*GNB + nb] = seg;
    }
  }
  __syncthreads();
  int rr = tid >> 2, w = tid & 3;
  if (row0 + rr < TOPN)
    bits[((size_t)b*TOPN + row0 + rr)*512 + (col0>>5) + w] = bitsL[rr][w];
}

__global__ void k7_rowstats(const float* __restrict__ psum, const float* __restrict__ pseg,
                            const float* __restrict__ vals, const int* __restrict__ cellA,
                            float* __restrict__ summ, float* __restrict__ scores, int* __restrict__ keepA){
  int t = blockIdx.x*blockDim.x + threadIdx.x;
  if (t >= NBATCH*TOPN) return;
  float sc = 0.f, sg = 0.f;
  for (int i = 0; i < GNB; ++i) { sc += psum[(size_t)t*GNB+i]; sg += pseg[(size_t)t*GNB+i]; }
  float v = vals[t];
  int cell = cellA[t];
  int lvl,g,y,x; cell_decode(cell,lvl,g,y,x);
  float stride = (lvl<=1)?8.f:(lvl==2)?16.f:32.f;
  bool keep = (v > 0.1f) && (sc > stride);
  float seg = sg / fmaxf(sc, 1e-6f);
  summ[t] = sc;
  scores[t] = keep ? v*seg : 0.f;
  keepA[t] = keep ? 1 : 0;
}

__global__ __launch_bounds__(512) void k8_order(const float* __restrict__ scores, int* __restrict__ order){
  __shared__ uint64_t key[512];
  int b = blockIdx.x, tid = threadIdx.x;
  uint64_t k = 0;
  if (tid < TOPN)
    k = ((uint64_t)__float_as_uint(scores[b*TOPN+tid]) << 32) | (uint64_t)(0xFFFFFFFFu - (uint32_t)tid);
  key[tid] = k;
  bitonic_desc<512,512>(key);
  if (tid < TOPN) order[b*TOPN+tid] = (int)(0xFFFFFFFFu - (uint32_t)(key[tid] & 0xFFFFFFFFu));
}

__global__ __launch_bounds__(256) void k9_dmat(const uint32_t* __restrict__ bitsG,
        const int* __restrict__ order, const int* __restrict__ labelA, const int* __restrict__ keepA,
        const float* __restrict__ summ, float* __restrict__ dmat){
  __shared__ uint32_t rowb[512];
  __shared__ int labL[TOPN];
  __shared__ int ojL[TOPN];
  __shared__ int redI[4];
  int i = blockIdx.x, b = blockIdx.y, tid = threadIdx.x;
  float* drow = dmat + ((size_t)b*TOPN + i)*TOPN;
  for (int j = tid; j < TOPN; j += 256) drow[j] = 0.f;
  int oi = order[b*TOPN + i];
  int ki = keepA[b*TOPN + oi];
  if (!ki) return;                 // uniform across block
  float si = summ[b*TOPN + oi];
  for (int w = tid; w < 512; w += 256) rowb[w] = bitsG[((size_t)b*TOPN + oi)*512 + w];
  for (int j = tid; j < TOPN; j += 256) {
    int oj = order[b*TOPN + j];
    ojL[j] = oj;
    labL[j] = keepA[b*TOPN + oj] ? labelA[b*TOPN + oj] : -1;
  }
  __syncthreads();
  int li = labL[i];
  for (int j = i+1; j < TOPN; ++j) {
    if (labL[j] != li) continue;
    int oj = ojL[j];
    int cc = 0;
    for (int w = tid; w < 512; w += 256)
      cc += __popc(rowb[w] & bitsG[((size_t)b*TOPN + oj)*512 + w]);
    #pragma unroll
    for (int d = 1; d < 64; d <<= 1) cc += __shfl_xor(cc, d);
    if ((tid & 63) == 0) redI[tid >> 6] = cc;
    __syncthreads();
    if (tid == 0) {
      float inter = (float)(redI[0]+redI[1]+redI[2]+redI[3]);
      float sj = summ[b*TOPN + oj];
      drow[j] = inter / fmaxf(si + sj - inter, 1e-6f);
    }
    __syncthreads();
  }
}

__global__ __launch_bounds__(512) void k10_comp(const float* __restrict__ dmat, float* __restrict__ comp){
  int b = blockIdx.x, j = threadIdx.x;
  if (j >= TOPN) return;
  float m = 0.f;
  for (int i = 0; i < TOPN; ++i) m = fmaxf(m, dmat[((size_t)b*TOPN+i)*TOPN + j]);
  comp[b*TOPN+j] = m;
}

__global__ __launch_bounds__(512) void k10_coef(const float* __restrict__ dmat, const float* __restrict__ comp,
        const float* __restrict__ scores, const int* __restrict__ order, const int* __restrict__ keepA,
        float* __restrict__ s2){
  __shared__ float e2c[TOPN];
  int b = blockIdx.x, tid = threadIdx.x;
  for (int i = tid; i < TOPN; i += 512) { float c = comp[b*TOPN+i]; e2c[i] = expf(-2.0f*c*c); }
  __syncthreads();
  if (tid >= TOPN) return;
  float mn = 1e30f;
  for (int i = 0; i < TOPN; ++i) {
    float d = dmat[((size_t)b*TOPN+i)*TOPN + tid];
    float r = expf(-2.0f*d*d) / e2c[i];
    mn = fminf(mn, r);
  }
  int oj = order[b*TOPN+tid];
  float s = scores[b*TOPN+oj] * mn;
  bool ok = (s >= 0.05f) && (s >= 0.1f) && (keepA[b*TOPN+oj] != 0);
  s2[b*TOPN+tid] = ok ? s : 0.f;
}

__global__ __launch_bounds__(512) void k11_top100(const float* __restrict__ s2, const int* __restrict__ order,
        const int* __restrict__ labelA, float* __restrict__ outF, int* __restrict__ selrow){
  __shared__ uint64_t key[512];
  int b = blockIdx.x, tid = threadIdx.x;
  uint64_t k = 0;
  if (tid < TOPN)
    k = ((uint64_t)__float_as_uint(s2[b*TOPN+tid]) << 32) | (uint64_t)(0xFFFFFFFFu - (uint32_t)tid);
  key[tid] = k;
  bitonic_desc<512,512>(key);
  if (tid < MAXM) {
    uint64_t kk = key[tid];
    float v = __uint_as_float((uint32_t)(kk >> 32));
    int j = (int)(0xFFFFFFFFu - (uint32_t)(kk & 0xFFFFFFFFu));
    if (j < 0 || j >= TOPN) { j = 0; v = 0.f; }
    int orow = order[b*TOPN + j];
    float lab = (v > 0.f) ? (float)labelA[b*TOPN + orow] : -1.0f;
    size_t maskCount = (size_t)NBATCH*MAXM*OUTH*OUTW;
    outF[maskCount + (size_t)b*MAXM + tid] = lab;
    outF[maskCount + (size_t)NBATCH*MAXM + (size_t)b*MAXM + tid] = v;
    selrow[b*MAXM + tid] = orow;
  }
}

__global__ __launch_bounds__(256) void k12_gemm2(const float* __restrict__ Kmat, const float* __restrict__ mf,
        const int* __restrict__ selrow, float* __restrict__ sigsel){
  __shared__ float As[BM][33];
  __shared__ float4 Bs4[32][BN/4];
  float* BsF = (float*)Bs4;
  int tid = threadIdx.x;
  int nb = blockIdx.x, mb = blockIdx.y, b = blockIdx.z;
  int row0 = mb*BM, col0 = nb*BN;
  int tx = tid & 15, ty = tid >> 4;
  float acc[4][8];
  #pragma unroll
  for (int i=0;i<4;i++)
    #pragma unroll
    for(int j=0;j<8;j++) acc[i][j]=0.f;
  for (int k0 = 0; k0 < CHN; k0 += 32) {
    __syncthreads();
    #pragma unroll
    for (int i = 0; i < 8; ++i) {
      int e = i*256 + tid;
      int r = e >> 5, kk = e & 31;
      float v = 0.f;
      int rr = row0 + r;
      if (rr < MAXM) v = Kmat[((size_t)b*TOPN + selrow[b*MAXM + rr])*CHN + k0 + kk];
      As[r][kk] = v;
    }
    #pragma unroll
    for (int i = 0; i < 16; ++i) {
      int e = i*256 + tid;
      int kk = e >> 7, col = e & 127;
      BsF[kk*BN + col] = mf[((size_t)b*CHN + k0 + kk)*HWN + col0 + col];
    }
    __syncthreads();
    #pragma unroll
    for (int kk = 0; kk < 32; ++kk) {
      float4 b0 = Bs4[kk][tx*2];
      float4 b1 = Bs4[kk][tx*2+1];
      #pragma unroll
      for (int i = 0; i < 4; ++i) {
        float a = As[ty*4+i][kk];
        acc[i][0] += a*b0.x; acc[i][1] += a*b0.y; acc[i][2] += a*b0.z; acc[i][3] += a*b0.w;
        acc[i][4] += a*b1.x; acc[i][5] += a*b1.y; acc[i][6] += a*b1.z; acc[i][7] += a*b1.w;
      }
    }
  }
  #pragma unroll
  for (int i = 0; i < 4; ++i) {
    int r = row0 + ty*4 + i;
    if (r < MAXM) {
      float4 s0 = make_float4(sigmoidf_(acc[i][0]), sigmoidf_(acc[i][1]), sigmoidf_(acc[i][2]), sigmoidf_(acc[i][3]));
      float4 s1 = make_float4(sigmoidf_(acc[i][4]), sigmoidf_(acc[i][5]), sigmoidf_(acc[i][6]), sigmoidf_(acc[i][7]));
      size_t base = ((size_t)b*MAXM + r)*HWN + col0 + tx*8;
      *(float4*)&sigsel[base]   = s0;
      *(float4*)&sigsel[base+4] = s1;
    }
  }
}

__global__ void k13_upsample(const float* __restrict__ sigsel, float* __restrict__ outF){
  int t = blockIdx.x*blockDim.x + threadIdx.x;
  const int XG = OUTW/4;
  int total = NBATCH*MAXM*OUTH*XG;
  if (t >= total) return;
  int xg = t % XG;
  int tmp = t / XG;
  int Y = tmp % OUTH;
  int tmp2 = tmp / OUTH;
  int r = tmp2 % MAXM;
  int b = tmp2 / MAXM;
  size_t maskCount = (size_t)NBATCH*MAXM*OUTH*OUTW;
  float fv = outF[maskCount + (size_t)NBATCH*MAXM + (size_t)b*MAXM + r];
  float4 o = make_float4(0.f,0.f,0.f,0.f);
  if (fv > 0.f) {
    const float* sm = sigsel + ((size_t)b*MAXM + r)*HWN;
    const float SC = (float)(127.0/511.0);
    float fy = (float)Y * SC;
    int ly = (int)floorf(fy); if (ly < 0) ly = 0; if (ly > HMM-1) ly = HMM-1;
    int hy = ly+1 < HMM ? ly+1 : HMM-1;
    float wy = fy - (float)ly;
    float res[4];
    #pragma unroll
    for (int u = 0; u < 4; ++u) {
      int X = xg*4 + u;
      float fx = (float)X * SC;
      int lx = (int)floorf(fx); if (lx < 0) lx = 0; if (lx > HMM-1) lx = HMM-1;
      int hx = lx+1 < HMM ? lx+1 : HMM-1;
      float wx = fx - (float)lx;
      float a = (1.f-wy)*sm[ly*HMM+lx] + wy*sm[hy*HMM+lx];
      float c = (1.f-wy)*sm[ly*HMM+hx] + wy*sm[hy*HMM+hx];
      float v = (1.f-wx)*a + wx*c;
      res[u] = (v > 0.5f) ? 1.f : 0.f;
    }
    o = make_float4(res[0],res[1],res[2],res[3]);
  }
  *(float4*)&outF[(((size_t)b*MAXM + r)*OUTH + Y)*OUTW + xg*4] = o;
}

extern "C" void kernel_launch(void* const* d_in, const int* in_sizes, int n_in,
                              void* d_out, int out_size, void* d_ws, size_t ws_size,
                              hipStream_t stream) {
  const float* mf = (const float*)d_in[0];
  const float *cate[5], *kern[5];
  // detect dict-order (interleaved) vs signature-order (grouped)
  bool interleaved = (n_in > 2) && (in_sizes[2] == NBATCH*CHN*40*40);
  if (interleaved) {
    for (int i = 0; i < 5; ++i) { cate[i] = (const float*)d_in[1 + 2*i]; kern[i] = (const float*)d_in[2 + 2*i]; }
  } else {
    for (int i = 0; i < 5; ++i) { cate[i] = (const float*)d_in[1 + i]; kern[i] = (const float*)d_in[6 + i]; }
  }
  float* outF = (float*)d_out;

  uint8_t* p = (uint8_t*)d_ws;
  auto alloc = [&](size_t bytes) -> void* {
    void* r = (void*)p;
    p += (bytes + 255) & ~(size_t)255;
    return r;
  };
  float*    cate_scores = (float*)   alloc((size_t)NBATCH*FLATN*4);
  uint32_t* hist        = (uint32_t*)alloc((size_t)NBATCH*NBINS*4);
  uint32_t* cnt         = (uint32_t*)alloc((size_t)NBATCH*4);
  int*      cutoff      = (int*)     alloc((size_t)NBATCH*4);
  float*    cval        = (float*)   alloc((size_t)NBATCH*CANDCAP*4);
  uint32_t* cidx        = (uint32_t*)alloc((size_t)NBATCH*CANDCAP*4);
  float*    vals        = (float*)   alloc((size_t)NBATCH*TOPN*4);
  int*      cellA       = (int*)     alloc((size_t)NBATCH*TOPN*4);
  int*      labelA      = (int*)     alloc((size_t)NBATCH*TOPN*4);
  float*    Kmat        = (float*)   alloc((size_t)NBATCH*TOPN*CHN*4);
  uint32_t* bits        = (uint32_t*)alloc((size_t)NBATCH*TOPN*512*4);
  float*    psum        = (float*)   alloc((size_t)NBATCH*TOPN*GNB*4);
  float*    pseg        = (float*)   alloc((size_t)NBATCH*TOPN*GNB*4);
  float*    summ        = (float*)   alloc((size_t)NBATCH*TOPN*4);
  float*    scores      = (float*)   alloc((size_t)NBATCH*TOPN*4);
  int*      keepA       = (int*)     alloc((size_t)NBATCH*TOPN*4);
  int*      order       = (int*)     alloc((size_t)NBATCH*TOPN*4);
  float*    dmat        = (float*)   alloc((size_t)NBATCH*TOPN*TOPN*4);
  float*    comp        = (float*)   alloc((size_t)NBATCH*TOPN*4);
  float*    s2          = (float*)   alloc((size_t)NBATCH*TOPN*4);
  int*      selrow      = (int*)     alloc((size_t)NBATCH*MAXM*4);
  float*    sigsel      = (float*)   alloc((size_t)NBATCH*MAXM*HWN*4);
  (void)ws_size; (void)out_size;

  hipLaunchKernelGGL(k0_init, dim3((NBATCH*NBINS + 255)/256), dim3(256), 0, stream, hist, cnt);
  hipLaunchKernelGGL(k1_scores, dim3((NBATCH*FLATN + 255)/256), dim3(256), 0, stream,
                     cate[0], cate[1], cate[2], cate[3], cate[4], cate_scores, hist);
  hipLaunchKernelGGL(k2_cutoff, dim3(NBATCH), dim3(1), 0, stream, hist, cutoff);
  hipLaunchKernelGGL(k3_gather, dim3((NBATCH*FLATN + 255)/256), dim3(256), 0, stream,
                     cate_scores, cutoff, cnt, cval, cidx);
  hipLaunchKernelGGL(k4_sort, dim3(NBATCH), dim3(1024), 0, stream, cnt, cval, cidx, vals, cellA, labelA);
  hipLaunchKernelGGL(k5_kmat, dim3((NBATCH*TOPN*CHN + 255)/256), dim3(256), 0, stream,
                     kern[0], kern[1], kern[2], kern[3], kern[4], cellA, Kmat);
  hipLaunchKernelGGL(k6_gemm1, dim3(GNB, (TOPN+BM-1)/BM, NBATCH), dim3(256), 0, stream,
                     Kmat, mf, bits, psum, pseg);
  hipLaunchKernelGGL(k7_rowstats, dim3((NBATCH*TOPN + 255)/256), dim3(256), 0, stream,
                     psum, pseg, vals, cellA, summ, scores, keepA);
  hipLaunchKernelGGL(k8_order, dim3(NBATCH), dim3(512), 0, stream, scores, order);
  hipLaunchKernelGGL(k9_dmat, dim3(TOPN, NBATCH), dim3(256), 0, stream,
                     bits, order, labelA, keepA, summ, dmat);
  hipLaunchKernelGGL(k10_comp, dim3(NBATCH), dim3(512), 0, stream, dmat, comp);
  hipLaunchKernelGGL(k10_coef, dim3(NBATCH), dim3(512), 0, stream,
                     dmat, comp, scores, order, keepA, s2);
  hipLaunchKernelGGL(k11_top100, dim3(NBATCH), dim3(512), 0, stream, s2, order, labelA, outF, selrow);
  hipLaunchKernelGGL(k12_gemm2, dim3(GNB, (MAXM+BM-1)/BM, NBATCH), dim3(256), 0, stream,
                     Kmat, mf, selrow, sigsel);
  hipLaunchKernelGGL(k13_upsample, dim3((NBATCH*MAXM*OUTH*(OUTW/4) + 255)/256), dim3(256), 0, stream,
                     sigsel, outF);
}

// Round 2
// 503.968 us; speedup vs baseline: 1.4073x; 1.4073x over previous
//
#include <hip/hip_runtime.h>
#include <math.h>
#include <stdint.h>

#define NBATCH 2
#define NC 80
#define CHN 256
#define HMM 128
#define HWN (HMM*HMM)
#define NCELL 3872
#define FLATN (NCELL*NC)
#define TOPN 500
#define MAXM 100
#define OUTH 512
#define OUTW 512
#define NBINS 1024
#define CANDCAP 2048
#define BM 128
#define BN 128
#define BK 32
#define GNB (HWN/BN)   // 128 N-blocks per row

__device__ __forceinline__ float sigmoidf_(float x){ return 1.0f/(1.0f+expf(-x)); }

__device__ __forceinline__ void cell_decode(int cell, int& lvl, int& g, int& y, int& x){
  int off;
  if (cell < 1600)      { lvl=0; g=40; off=0; }
  else if (cell < 2896) { lvl=1; g=36; off=1600; }
  else if (cell < 3472) { lvl=2; g=24; off=2896; }
  else if (cell < 3728) { lvl=3; g=16; off=3472; }
  else                  { lvl=4; g=12; off=3728; }
  int r = cell - off; y = r / g; x = r - y*g;
}

template<int N, int NT>
__device__ __forceinline__ void bitonic_desc(uint64_t* key){
  int tid = threadIdx.x;
  for (int k = 2; k <= N; k <<= 1)
    for (int j = k >> 1; j > 0; j >>= 1) {
      __syncthreads();
      for (int e = tid; e < N; e += NT) {
        int l = e ^ j;
        if (l > e) {
          uint64_t a = key[e], c = key[l];
          bool up = ((e & k) == 0);
          if (up ? (a < c) : (a > c)) { key[e] = c; key[l] = a; }
        }
      }
    }
  __syncthreads();
}

__global__ void k0_init(uint32_t* hist, uint32_t* cnt){
  int t = blockIdx.x*blockDim.x + threadIdx.x;
  if (t < NBATCH*NBINS) hist[t] = 0;
  if (t < NBATCH) cnt[t] = 0;
}

__global__ void k1_scores(const float* __restrict__ c0, const float* __restrict__ c1,
                          const float* __restrict__ c2, const float* __restrict__ c3,
                          const float* __restrict__ c4,
                          float* __restrict__ scores, uint32_t* __restrict__ hist){
  int t = blockIdx.x*blockDim.x + threadIdx.x;
  if (t >= NBATCH*FLATN) return;
  int b = t / FLATN;
  int rem = t - b*FLATN;
  int cell = rem / NC;
  int c = rem - cell*NC;
  int lvl,g,y,x; cell_decode(cell,lvl,g,y,x);
  const float* cp = lvl==0?c0:lvl==1?c1:lvl==2?c2:lvl==3?c3:c4;
  const float* base = cp + (size_t)(b*NC + c)*g*g;
  float raw = base[y*g + x];
  float m = raw;
  if (y > 0)          m = fmaxf(m, base[(y-1)*g + x]);
  if (x > 0)          m = fmaxf(m, base[y*g + x-1]);
  if (y > 0 && x > 0) m = fmaxf(m, base[(y-1)*g + x-1]);
  float s = (raw == m) ? sigmoidf_(raw) : 0.0f;
  scores[t] = s;
  if (s > 0.1f) {
    int bin = (int)(s * 1024.0f); if (bin > NBINS-1) bin = NBINS-1;
    atomicAdd(&hist[b*NBINS + bin], 1u);
  }
}

__global__ __launch_bounds__(1024) void k2_cutoff(const uint32_t* __restrict__ hist, int* __restrict__ cutoff){
  __shared__ uint32_t h[NBINS];
  int b = blockIdx.x;
  h[threadIdx.x] = hist[b*NBINS + threadIdx.x];
  __syncthreads();
  if (threadIdx.x == 0) {
    int acc = 0; int cut = 0;
    for (int d = NBINS-1; d >= 0; --d) {
      acc += (int)h[d];
      if (acc >= TOPN) { cut = d; break; }
    }
    cutoff[b] = cut;
  }
}

__global__ void k3_gather(const float* __restrict__ scores, const int* __restrict__ cutoff,
                          uint32_t* __restrict__ cnt, float* __restrict__ cval, uint32_t* __restrict__ cidx){
  int t = blockIdx.x*blockDim.x + threadIdx.x;
  if (t >= NBATCH*FLATN) return;
  int b = t / FLATN; int idx = t - b*FLATN;
  float v = scores[t];
  if (v > 0.1f) {
    int bin = (int)(v * 1024.0f); if (bin > NBINS-1) bin = NBINS-1;
    if (bin >= cutoff[b]) {
      uint32_t p = atomicAdd(&cnt[b], 1u);
      if (p < CANDCAP) { cval[b*CANDCAP+p] = v; cidx[b*CANDCAP+p] = (uint32_t)idx; }
    }
  }
}

__global__ __launch_bounds__(1024) void k4_sort(const uint32_t* __restrict__ cnt,
        const float* __restrict__ cval, const uint32_t* __restrict__ cidx,
        float* __restrict__ vals, int* __restrict__ cellA, int* __restrict__ labelA){
  __shared__ uint64_t key[CANDCAP];
  int b = blockIdx.x; int tid = threadIdx.x;
  int n = (int)cnt[b]; if (n > CANDCAP) n = CANDCAP;
  for (int e = tid; e < CANDCAP; e += 1024) {
    uint64_t k = 0;
    if (e < n)
      k = ((uint64_t)__float_as_uint(cval[b*CANDCAP+e]) << 32) |
          (uint64_t)(0xFFFFFFFFu - cidx[b*CANDCAP+e]);
    key[e] = k;
  }
  bitonic_desc<CANDCAP,1024>(key);
  for (int r = tid; r < TOPN; r += 1024) {
    uint64_t k = key[r];
    if ((k >> 32) == 0) { vals[b*TOPN+r] = -1.0f; cellA[b*TOPN+r] = 0; labelA[b*TOPN+r] = 0; }
    else {
      uint32_t idx = 0xFFFFFFFFu - (uint32_t)(k & 0xFFFFFFFFu);
      vals[b*TOPN+r]   = __uint_as_float((uint32_t)(k >> 32));
      cellA[b*TOPN+r]  = (int)(idx / NC);
      labelA[b*TOPN+r] = (int)(idx % NC);
    }
  }
}

__global__ void k5_kmat(const float* __restrict__ k0p, const float* __restrict__ k1p,
                        const float* __restrict__ k2p, const float* __restrict__ k3p,
                        const float* __restrict__ k4p,
                        const int* __restrict__ cellA, float* __restrict__ Kmat){
  int t = blockIdx.x*blockDim.x + threadIdx.x;
  if (t >= NBATCH*TOPN*CHN) return;
  int b = t / (TOPN*CHN); int rem = t - b*(TOPN*CHN);
  int k = rem / CHN; int c = rem - k*CHN;
  int cell = cellA[b*TOPN + k];
  int lvl,g,y,x; cell_decode(cell,lvl,g,y,x);
  const float* kp = lvl==0?k0p:lvl==1?k1p:lvl==2?k2p:lvl==3?k3p:k4p;
  Kmat[t] = kp[((size_t)(b*CHN + c)*g + y)*g + x];
}

// 128x128 tile, 256 threads, 8x8 micro-tile per thread.
// thread cols: [tx*4, tx*4+3] and [64+tx*4, 64+tx*4+3]; rows ty*8..ty*8+7.
__global__ __launch_bounds__(256) void k6_gemm1(const float* __restrict__ Kmat, const float* __restrict__ mf,
        uint32_t* __restrict__ bits, float* __restrict__ psum, float* __restrict__ pseg){
  __shared__ float As[BM][BK+1];
  __shared__ float Bs[BK][BN];
  __shared__ uint32_t bitsL[BM][4];
  int tid = threadIdx.x;
  int nb = blockIdx.x, mb = blockIdx.y, b = blockIdx.z;
  int row0 = mb*BM, col0 = nb*BN;
  int tx = tid & 15, ty = tid >> 4;
  for (int i = tid; i < BM*4; i += 256) ((uint32_t*)bitsL)[i] = 0;
  float acc[8][8];
  #pragma unroll
  for (int i=0;i<8;i++)
    #pragma unroll
    for(int j=0;j<8;j++) acc[i][j]=0.f;
  for (int k0 = 0; k0 < CHN; k0 += BK) {
    __syncthreads();
    #pragma unroll
    for (int i = 0; i < 16; ++i) {
      int e = i*256 + tid;
      int r = e >> 5, kk = e & 31;
      float v = 0.f;
      if (row0 + r < TOPN) v = Kmat[((size_t)b*TOPN + row0 + r)*CHN + k0 + kk];
      As[r][kk] = v;
    }
    #pragma unroll
    for (int i = 0; i < 4; ++i) {
      int e = i*256 + tid;
      int kk = e >> 5, c4 = e & 31;
      float4 v = *(const float4*)&mf[((size_t)b*CHN + k0 + kk)*HWN + col0 + c4*4];
      *(float4*)&Bs[kk][c4*4] = v;
    }
    __syncthreads();
    #pragma unroll 4
    for (int kk = 0; kk < BK; ++kk) {
      float a[8];
      #pragma unroll
      for (int i = 0; i < 8; ++i) a[i] = As[ty*8+i][kk];
      float4 b0 = *(float4*)&Bs[kk][tx*4];
      float4 b1 = *(float4*)&Bs[kk][64+tx*4];
      #pragma unroll
      for (int i = 0; i < 8; ++i) {
        acc[i][0] += a[i]*b0.x; acc[i][1] += a[i]*b0.y; acc[i][2] += a[i]*b0.z; acc[i][3] += a[i]*b0.w;
        acc[i][4] += a[i]*b1.x; acc[i][5] += a[i]*b1.y; acc[i][6] += a[i]*b1.z; acc[i][7] += a[i]*b1.w;
      }
    }
  }
  // epilogue: sigmoid, bit-pack, per-row count & seg-sum
  int w1 = tx >> 3;                    // word for cols [tx*4 .. +3]
  int sh = (tx*4) & 31;
  #pragma unroll
  for (int i = 0; i < 8; ++i) {
    int r = row0 + ty*8 + i;
    uint32_t mb1 = 0, mb2 = 0; float seg = 0.f; int cc = 0;
    #pragma unroll
    for (int j = 0; j < 4; ++j) {
      float s0 = sigmoidf_(acc[i][j]);
      float s1 = sigmoidf_(acc[i][4+j]);
      if (s0 > 0.5f) { mb1 |= (1u << j); seg += s0; cc++; }
      if (s1 > 0.5f) { mb2 |= (1u << j); seg += s1; cc++; }
    }
    if (r < TOPN) {
      atomicOr(&bitsL[ty*8+i][w1],     mb1 << sh);
      atomicOr(&bitsL[ty*8+i][2+w1],   mb2 << sh);
    }
    #pragma unroll
    for (int d = 1; d < 16; d <<= 1) {
      seg += __shfl_xor(seg, d);
      cc  += __shfl_xor(cc, d);
    }
    if (tx == 0 && r < TOPN) {
      psum[((size_t)b*TOPN + r)*GNB + nb] = (float)cc;
      pseg[((size_t)b*TOPN + r)*GNB + nb] = seg;
    }
  }
  __syncthreads();
  for (int e = tid; e < BM*4; e += 256) {
    int rr = e >> 2, w = e & 3;
    if (row0 + rr < TOPN)
      bits[((size_t)b*TOPN + row0 + rr)*512 + (col0>>5) + w] = bitsL[rr][w];
  }
}

__global__ void k7_rowstats(const float* __restrict__ psum, const float* __restrict__ pseg,
                            const float* __restrict__ vals, const int* __restrict__ cellA,
                            float* __restrict__ summ, float* __restrict__ scores, int* __restrict__ keepA){
  int t = blockIdx.x*blockDim.x + threadIdx.x;
  if (t >= NBATCH*TOPN) return;
  float sc = 0.f, sg = 0.f;
  for (int i = 0; i < GNB; i += 4) {
    float4 a = *(const float4*)&psum[(size_t)t*GNB+i];
    float4 c = *(const float4*)&pseg[(size_t)t*GNB+i];
    sc += a.x+a.y+a.z+a.w; sg += c.x+c.y+c.z+c.w;
  }
  float v = vals[t];
  int cell = cellA[t];
  int lvl,g,y,x; cell_decode(cell,lvl,g,y,x);
  float stride = (lvl<=1)?8.f:(lvl==2)?16.f:32.f;
  bool keep = (v > 0.1f) && (sc > stride);
  float seg = sg / fmaxf(sc, 1e-6f);
  summ[t] = sc;
  scores[t] = keep ? v*seg : 0.f;
  keepA[t] = keep ? 1 : 0;
}

__global__ __launch_bounds__(512) void k8_order(const float* __restrict__ scores, int* __restrict__ order){
  __shared__ uint64_t key[512];
  int b = blockIdx.x, tid = threadIdx.x;
  uint64_t k = 0;
  if (tid < TOPN)
    k = ((uint64_t)__float_as_uint(scores[b*TOPN+tid]) << 32) | (uint64_t)(0xFFFFFFFFu - (uint32_t)tid);
  key[tid] = k;
  bitonic_desc<512,512>(key);
  if (tid < TOPN) order[b*TOPN+tid] = (int)(0xFFFFFFFFu - (uint32_t)(key[tid] & 0xFFFFFFFFu));
}

__global__ __launch_bounds__(256) void k9_dmat(const uint32_t* __restrict__ bitsG,
        const int* __restrict__ order, const int* __restrict__ labelA, const int* __restrict__ keepA,
        const float* __restrict__ summ, float* __restrict__ dmat){
  __shared__ uint32_t rowb[512];
  __shared__ int labL[TOPN];
  __shared__ int ojL[TOPN];
  __shared__ int redI[4];
  int i = blockIdx.x, b = blockIdx.y, tid = threadIdx.x;
  float* drow = dmat + ((size_t)b*TOPN + i)*TOPN;
  for (int j = tid; j < TOPN; j += 256) drow[j] = 0.f;
  int oi = order[b*TOPN + i];
  int ki = keepA[b*TOPN + oi];
  if (!ki) return;                 // uniform across block
  float si = summ[b*TOPN + oi];
  for (int w = tid; w < 512; w += 256) rowb[w] = bitsG[((size_t)b*TOPN + oi)*512 + w];
  for (int j = tid; j < TOPN; j += 256) {
    int oj = order[b*TOPN + j];
    ojL[j] = oj;
    labL[j] = keepA[b*TOPN + oj] ? labelA[b*TOPN + oj] : -1;
  }
  __syncthreads();
  int li = labL[i];
  for (int j = i+1; j < TOPN; ++j) {
    if (labL[j] != li) continue;
    int oj = ojL[j];
    int cc = 0;
    for (int w = tid; w < 512; w += 256)
      cc += __popc(rowb[w] & bitsG[((size_t)b*TOPN + oj)*512 + w]);
    #pragma unroll
    for (int d = 1; d < 64; d <<= 1) cc += __shfl_xor(cc, d);
    if ((tid & 63) == 0) redI[tid >> 6] = cc;
    __syncthreads();
    if (tid == 0) {
      float inter = (float)(redI[0]+redI[1]+redI[2]+redI[3]);
      float sj = summ[b*TOPN + oj];
      drow[j] = inter / fmaxf(si + sj - inter, 1e-6f);
    }
    __syncthreads();
  }
}

__global__ __launch_bounds__(256) void k10_comp(const float* __restrict__ dmat,
        float* __restrict__ comp, float* __restrict__ e2c){
  __shared__ float red[4];
  int j = blockIdx.x, b = blockIdx.y, tid = threadIdx.x;
  float m = 0.f;
  for (int i = tid; i < TOPN; i += 256) m = fmaxf(m, dmat[((size_t)b*TOPN+i)*TOPN + j]);
  #pragma unroll
  for (int d = 1; d < 64; d <<= 1) m = fmaxf(m, __shfl_xor(m, d));
  if ((tid & 63) == 0) red[tid >> 6] = m;
  __syncthreads();
  if (tid == 0) {
    m = fmaxf(fmaxf(red[0], red[1]), fmaxf(red[2], red[3]));
    comp[b*TOPN+j] = m;
    e2c[b*TOPN+j] = expf(-2.0f*m*m);
  }
}

__global__ __launch_bounds__(256) void k10_coef(const float* __restrict__ dmat, const float* __restrict__ e2c,
        const float* __restrict__ scores, const int* __restrict__ order, const int* __restrict__ keepA,
        float* __restrict__ s2){
  __shared__ float red[4];
  int j = blockIdx.x, b = blockIdx.y, tid = threadIdx.x;
  float mn = 1e30f;
  for (int i = tid; i < TOPN; i += 256) {
    float d = dmat[((size_t)b*TOPN+i)*TOPN + j];
    float r = expf(-2.0f*d*d) / e2c[b*TOPN+i];
    mn = fminf(mn, r);
  }
  #pragma unroll
  for (int d = 1; d < 64; d <<= 1) mn = fminf(mn, __shfl_xor(mn, d));
  if ((tid & 63) == 0) red[tid >> 6] = mn;
  __syncthreads();
  if (tid == 0) {
    mn = fminf(fminf(red[0], red[1]), fminf(red[2], red[3]));
    int oj = order[b*TOPN+j];
    float s = scores[b*TOPN+oj] * mn;
    bool ok = (s >= 0.05f) && (s >= 0.1f) && (keepA[b*TOPN+oj] != 0);
    s2[b*TOPN+j] = ok ? s : 0.f;
  }
}

__global__ __launch_bounds__(512) void k11_top100(const float* __restrict__ s2, const int* __restrict__ order,
        const int* __restrict__ labelA, float* __restrict__ outF, int* __restrict__ selrow){
  __shared__ uint64_t key[512];
  int b = blockIdx.x, tid = threadIdx.x;
  uint64_t k = 0;
  if (tid < TOPN)
    k = ((uint64_t)__float_as_uint(s2[b*TOPN+tid]) << 32) | (uint64_t)(0xFFFFFFFFu - (uint32_t)tid);
  key[tid] = k;
  bitonic_desc<512,512>(key);
  if (tid < MAXM) {
    uint64_t kk = key[tid];
    float v = __uint_as_float((uint32_t)(kk >> 32));
    int j = (int)(0xFFFFFFFFu - (uint32_t)(kk & 0xFFFFFFFFu));
    if (j < 0 || j >= TOPN) { j = 0; v = 0.f; }
    int orow = order[b*TOPN + j];
    float lab = (v > 0.f) ? (float)labelA[b*TOPN + orow] : -1.0f;
    size_t maskCount = (size_t)NBATCH*MAXM*OUTH*OUTW;
    outF[maskCount + (size_t)b*MAXM + tid] = lab;
    outF[maskCount + (size_t)NBATCH*MAXM + (size_t)b*MAXM + tid] = v;
    selrow[b*MAXM + tid] = orow;
  }
}

__global__ __launch_bounds__(256) void k12_gemm2(const float* __restrict__ Kmat, const float* __restrict__ mf,
        const int* __restrict__ selrow, float* __restrict__ sigsel){
  __shared__ float As[BM][BK+1];
  __shared__ float Bs[BK][BN];
  __shared__ int selL[BM];
  int tid = threadIdx.x;
  int nb = blockIdx.x, b = blockIdx.z;
  int col0 = nb*BN;
  int tx = tid & 15, ty = tid >> 4;
  if (tid < BM) selL[tid] = (tid < MAXM) ? selrow[b*MAXM + tid] : 0;
  float acc[8][8];
  #pragma unroll
  for (int i=0;i<8;i++)
    #pragma unroll
    for(int j=0;j<8;j++) acc[i][j]=0.f;
  __syncthreads();
  for (int k0 = 0; k0 < CHN; k0 += BK) {
    __syncthreads();
    #pragma unroll
    for (int i = 0; i < 16; ++i) {
      int e = i*256 + tid;
      int r = e >> 5, kk = e & 31;
      float v = 0.f;
      if (r < MAXM) v = Kmat[((size_t)b*TOPN + selL[r])*CHN + k0 + kk];
      As[r][kk] = v;
    }
    #pragma unroll
    for (int i = 0; i < 4; ++i) {
      int e = i*256 + tid;
      int kk = e >> 5, c4 = e & 31;
      float4 v = *(const float4*)&mf[((size_t)b*CHN + k0 + kk)*HWN + col0 + c4*4];
      *(float4*)&Bs[kk][c4*4] = v;
    }
    __syncthreads();
    #pragma unroll 4
    for (int kk = 0; kk < BK; ++kk) {
      float a[8];
      #pragma unroll
      for (int i = 0; i < 8; ++i) a[i] = As[ty*8+i][kk];
      float4 b0 = *(float4*)&Bs[kk][tx*4];
      float4 b1 = *(float4*)&Bs[kk][64+tx*4];
      #pragma unroll
      for (int i = 0; i < 8; ++i) {
        acc[i][0] += a[i]*b0.x; acc[i][1] += a[i]*b0.y; acc[i][2] += a[i]*b0.z; acc[i][3] += a[i]*b0.w;
        acc[i][4] += a[i]*b1.x; acc[i][5] += a[i]*b1.y; acc[i][6] += a[i]*b1.z; acc[i][7] += a[i]*b1.w;
      }
    }
  }
  #pragma unroll
  for (int i = 0; i < 8; ++i) {
    int r = ty*8 + i;
    if (r < MAXM) {
      float4 s0 = make_float4(sigmoidf_(acc[i][0]), sigmoidf_(acc[i][1]), sigmoidf_(acc[i][2]), sigmoidf_(acc[i][3]));
      float4 s1 = make_float4(sigmoidf_(acc[i][4]), sigmoidf_(acc[i][5]), sigmoidf_(acc[i][6]), sigmoidf_(acc[i][7]));
      size_t base = ((size_t)b*MAXM + r)*HWN + col0;
      *(float4*)&sigsel[base + tx*4]      = s0;
      *(float4*)&sigsel[base + 64 + tx*4] = s1;
    }
  }
}

__global__ void k13_upsample(const float* __restrict__ sigsel, float* __restrict__ outF){
  int t = blockIdx.x*blockDim.x + threadIdx.x;
  const int XG = OUTW/4;
  int total = NBATCH*MAXM*OUTH*XG;
  if (t >= total) return;
  int xg = t % XG;
  int tmp = t / XG;
  int Y = tmp % OUTH;
  int tmp2 = tmp / OUTH;
  int r = tmp2 % MAXM;
  int b = tmp2 / MAXM;
  size_t maskCount = (size_t)NBATCH*MAXM*OUTH*OUTW;
  float fv = outF[maskCount + (size_t)NBATCH*MAXM + (size_t)b*MAXM + r];
  float4 o = make_float4(0.f,0.f,0.f,0.f);
  if (fv > 0.f) {
    const float* sm = sigsel + ((size_t)b*MAXM + r)*HWN;
    const float SC = (float)(127.0/511.0);
    float fy = (float)Y * SC;
    int ly = (int)floorf(fy); if (ly < 0) ly = 0; if (ly > HMM-1) ly = HMM-1;
    int hy = ly+1 < HMM ? ly+1 : HMM-1;
    float wy = fy - (float)ly;
    float res[4];
    #pragma unroll
    for (int u = 0; u < 4; ++u) {
      int X = xg*4 + u;
      float fx = (float)X * SC;
      int lx = (int)floorf(fx); if (lx < 0) lx = 0; if (lx > HMM-1) lx = HMM-1;
      int hx = lx+1 < HMM ? lx+1 : HMM-1;
      float wx = fx - (float)lx;
      float a = (1.f-wy)*sm[ly*HMM+lx] + wy*sm[hy*HMM+lx];
      float c = (1.f-wy)*sm[ly*HMM+hx] + wy*sm[hy*HMM+hx];
      float v = (1.f-wx)*a + wx*c;
      res[u] = (v > 0.5f) ? 1.f : 0.f;
    }
    o = make_float4(res[0],res[1],res[2],res[3]);
  }
  *(float4*)&outF[(((size_t)b*MAXM + r)*OUTH + Y)*OUTW + xg*4] = o;
}

extern "C" void kernel_launch(void* const* d_in, const int* in_sizes, int n_in,
                              void* d_out, int out_size, void* d_ws, size_t ws_size,
                              hipStream_t stream) {
  const float* mf = (const float*)d_in[0];
  const float *cate[5], *kern[5];
  bool interleaved = (n_in > 2) && (in_sizes[2] == NBATCH*CHN*40*40);
  if (interleaved) {
    for (int i = 0; i < 5; ++i) { cate[i] = (const float*)d_in[1 + 2*i]; kern[i] = (const float*)d_in[2 + 2*i]; }
  } else {
    for (int i = 0; i < 5; ++i) { cate[i] = (const float*)d_in[1 + i]; kern[i] = (const float*)d_in[6 + i]; }
  }
  float* outF = (float*)d_out;

  uint8_t* p = (uint8_t*)d_ws;
  auto alloc = [&](size_t bytes) -> void* {
    void* r = (void*)p;
    p += (bytes + 255) & ~(size_t)255;
    return r;
  };
  float*    cate_scores = (float*)   alloc((size_t)NBATCH*FLATN*4);
  uint32_t* hist        = (uint32_t*)alloc((size_t)NBATCH*NBINS*4);
  uint32_t* cnt         = (uint32_t*)alloc((size_t)NBATCH*4);
  int*      cutoff      = (int*)     alloc((size_t)NBATCH*4);
  float*    cval        = (float*)   alloc((size_t)NBATCH*CANDCAP*4);
  uint32_t* cidx        = (uint32_t*)alloc((size_t)NBATCH*CANDCAP*4);
  float*    vals        = (float*)   alloc((size_t)NBATCH*TOPN*4);
  int*      cellA       = (int*)     alloc((size_t)NBATCH*TOPN*4);
  int*      labelA      = (int*)     alloc((size_t)NBATCH*TOPN*4);
  float*    Kmat        = (float*)   alloc((size_t)NBATCH*TOPN*CHN*4);
  uint32_t* bits        = (uint32_t*)alloc((size_t)NBATCH*TOPN*512*4);
  float*    psum        = (float*)   alloc((size_t)NBATCH*TOPN*GNB*4);
  float*    pseg        = (float*)   alloc((size_t)NBATCH*TOPN*GNB*4);
  float*    summ        = (float*)   alloc((size_t)NBATCH*TOPN*4);
  float*    scores      = (float*)   alloc((size_t)NBATCH*TOPN*4);
  int*      keepA       = (int*)     alloc((size_t)NBATCH*TOPN*4);
  int*      order       = (int*)     alloc((size_t)NBATCH*TOPN*4);
  float*    dmat        = (float*)   alloc((size_t)NBATCH*TOPN*TOPN*4);
  float*    comp        = (float*)   alloc((size_t)NBATCH*TOPN*4);
  float*    e2c         = (float*)   alloc((size_t)NBATCH*TOPN*4);
  float*    s2          = (float*)   alloc((size_t)NBATCH*TOPN*4);
  int*      selrow      = (int*)     alloc((size_t)NBATCH*MAXM*4);
  float*    sigsel      = (float*)   alloc((size_t)NBATCH*MAXM*HWN*4);
  (void)ws_size; (void)out_size;

  hipLaunchKernelGGL(k0_init, dim3((NBATCH*NBINS + 255)/256), dim3(256), 0, stream, hist, cnt);
  hipLaunchKernelGGL(k1_scores, dim3((NBATCH*FLATN + 255)/256), dim3(256), 0, stream,
                     cate[0], cate[1], cate[2], cate[3], cate[4], cate_scores, hist);
  hipLaunchKernelGGL(k2_cutoff, dim3(NBATCH), dim3(1024), 0, stream, hist, cutoff);
  hipLaunchKernelGGL(k3_gather, dim3((NBATCH*FLATN + 255)/256), dim3(256), 0, stream,
                     cate_scores, cutoff, cnt, cval, cidx);
  hipLaunchKernelGGL(k4_sort, dim3(NBATCH), dim3(1024), 0, stream, cnt, cval, cidx, vals, cellA, labelA);
  hipLaunchKernelGGL(k5_kmat, dim3((NBATCH*TOPN*CHN + 255)/256), dim3(256), 0, stream,
                     kern[0], kern[1], kern[2], kern[3], kern[4], cellA, Kmat);
  hipLaunchKernelGGL(k6_gemm1, dim3(GNB, (TOPN+BM-1)/BM, NBATCH), dim3(256), 0, stream,
                     Kmat, mf, bits, psum, pseg);
  hipLaunchKernelGGL(k7_rowstats, dim3((NBATCH*TOPN + 255)/256), dim3(256), 0, stream,
                     psum, pseg, vals, cellA, summ, scores, keepA);
  hipLaunchKernelGGL(k8_order, dim3(NBATCH), dim3(512), 0, stream, scores, order);
  hipLaunchKernelGGL(k9_dmat, dim3(TOPN, NBATCH), dim3(256), 0, stream,
                     bits, order, labelA, keepA, summ, dmat);
  hipLaunchKernelGGL(k10_comp, dim3(TOPN, NBATCH), dim3(256), 0, stream, dmat, comp, e2c);
  hipLaunchKernelGGL(k10_coef, dim3(TOPN, NBATCH), dim3(256), 0, stream,
                     dmat, e2c, scores, order, keepA, s2);
  hipLaunchKernelGGL(k11_top100, dim3(NBATCH), dim3(512), 0, stream, s2, order, labelA, outF, selrow);
  hipLaunchKernelGGL(k12_gemm2, dim3(GNB, 1, NBATCH), dim3(256), 0, stream,
                     Kmat, mf, selrow, sigsel);
  hipLaunchKernelGGL(k13_upsample, dim3((NBATCH*MAXM*OUTH*(OUTW/4) + 255)/256), dim3(256), 0, stream,
                     sigsel, outF);
}

// Round 3
// 457.693 us; speedup vs baseline: 1.5496x; 1.1011x over previous
//
#include <hip/hip_runtime.h>
#include <math.h>
#include <stdint.h>

#define NBATCH 2
#define NC 80
#define CHN 256
#define HMM 128
#define HWN (HMM*HMM)
#define NCELL 3872
#define FLATN (NCELL*NC)
#define TOPN 500
#define MAXM 100
#define OUTH 512
#define OUTW 512
#define NBINS 1024
#define CANDCAP 2048
#define BM 128
#define BN 128
#define BK 32
#define GNB (HWN/BN)   // 128 N-blocks per row

__device__ __forceinline__ float sigmoidf_(float x){ return 1.0f/(1.0f+expf(-x)); }

__device__ __forceinline__ void cell_decode(int cell, int& lvl, int& g, int& y, int& x){
  int off;
  if (cell < 1600)      { lvl=0; g=40; off=0; }
  else if (cell < 2896) { lvl=1; g=36; off=1600; }
  else if (cell < 3472) { lvl=2; g=24; off=2896; }
  else if (cell < 3728) { lvl=3; g=16; off=3472; }
  else                  { lvl=4; g=12; off=3728; }
  int r = cell - off; y = r / g; x = r - y*g;
}

template<int N, int NT>
__device__ __forceinline__ void bitonic_desc(uint64_t* key){
  int tid = threadIdx.x;
  for (int k = 2; k <= N; k <<= 1)
    for (int j = k >> 1; j > 0; j >>= 1) {
      __syncthreads();
      for (int e = tid; e < N; e += NT) {
        int l = e ^ j;
        if (l > e) {
          uint64_t a = key[e], c = key[l];
          bool up = ((e & k) == 0);
          if (up ? (a < c) : (a > c)) { key[e] = c; key[l] = a; }
        }
      }
    }
  __syncthreads();
}

__global__ void k0_init(uint32_t* hist, uint32_t* cnt){
  int t = blockIdx.x*blockDim.x + threadIdx.x;
  if (t < NBATCH*NBINS) hist[t] = 0;
  if (t < NBATCH) cnt[t] = 0;
}

__global__ void k1_scores(const float* __restrict__ c0, const float* __restrict__ c1,
                          const float* __restrict__ c2, const float* __restrict__ c3,
                          const float* __restrict__ c4,
                          float* __restrict__ scores, uint32_t* __restrict__ hist){
  int t = blockIdx.x*blockDim.x + threadIdx.x;
  if (t >= NBATCH*FLATN) return;
  int b = t / FLATN;
  int rem = t - b*FLATN;
  int cell = rem / NC;
  int c = rem - cell*NC;
  int lvl,g,y,x; cell_decode(cell,lvl,g,y,x);
  const float* cp = lvl==0?c0:lvl==1?c1:lvl==2?c2:lvl==3?c3:c4;
  const float* base = cp + (size_t)(b*NC + c)*g*g;
  float raw = base[y*g + x];
  float m = raw;
  if (y > 0)          m = fmaxf(m, base[(y-1)*g + x]);
  if (x > 0)          m = fmaxf(m, base[y*g + x-1]);
  if (y > 0 && x > 0) m = fmaxf(m, base[(y-1)*g + x-1]);
  float s = (raw == m) ? sigmoidf_(raw) : 0.0f;
  scores[t] = s;
  if (s > 0.1f) {
    int bin = (int)(s * 1024.0f); if (bin > NBINS-1) bin = NBINS-1;
    atomicAdd(&hist[b*NBINS + bin], 1u);
  }
}

__global__ __launch_bounds__(1024) void k2_cutoff(const uint32_t* __restrict__ hist, int* __restrict__ cutoff){
  __shared__ uint32_t h[NBINS];
  int b = blockIdx.x;
  h[threadIdx.x] = hist[b*NBINS + threadIdx.x];
  __syncthreads();
  if (threadIdx.x == 0) {
    int acc = 0; int cut = 0;
    for (int d = NBINS-1; d >= 0; --d) {
      acc += (int)h[d];
      if (acc >= TOPN) { cut = d; break; }
    }
    cutoff[b] = cut;
  }
}

__global__ void k3_gather(const float* __restrict__ scores, const int* __restrict__ cutoff,
                          uint32_t* __restrict__ cnt, float* __restrict__ cval, uint32_t* __restrict__ cidx){
  int t = blockIdx.x*blockDim.x + threadIdx.x;
  if (t >= NBATCH*FLATN) return;
  int b = t / FLATN; int idx = t - b*FLATN;
  float v = scores[t];
  if (v > 0.1f) {
    int bin = (int)(v * 1024.0f); if (bin > NBINS-1) bin = NBINS-1;
    if (bin >= cutoff[b]) {
      uint32_t p = atomicAdd(&cnt[b], 1u);
      if (p < CANDCAP) { cval[b*CANDCAP+p] = v; cidx[b*CANDCAP+p] = (uint32_t)idx; }
    }
  }
}

__global__ __launch_bounds__(1024) void k4_sort(const uint32_t* __restrict__ cnt,
        const float* __restrict__ cval, const uint32_t* __restrict__ cidx,
        float* __restrict__ vals, int* __restrict__ cellA, int* __restrict__ labelA){
  __shared__ uint64_t key[CANDCAP];
  int b = blockIdx.x; int tid = threadIdx.x;
  int n = (int)cnt[b]; if (n > CANDCAP) n = CANDCAP;
  for (int e = tid; e < CANDCAP; e += 1024) {
    uint64_t k = 0;
    if (e < n)
      k = ((uint64_t)__float_as_uint(cval[b*CANDCAP+e]) << 32) |
          (uint64_t)(0xFFFFFFFFu - cidx[b*CANDCAP+e]);
    key[e] = k;
  }
  bitonic_desc<CANDCAP,1024>(key);
  for (int r = tid; r < TOPN; r += 1024) {
    uint64_t k = key[r];
    if ((k >> 32) == 0) { vals[b*TOPN+r] = -1.0f; cellA[b*TOPN+r] = 0; labelA[b*TOPN+r] = 0; }
    else {
      uint32_t idx = 0xFFFFFFFFu - (uint32_t)(k & 0xFFFFFFFFu);
      vals[b*TOPN+r]   = __uint_as_float((uint32_t)(k >> 32));
      cellA[b*TOPN+r]  = (int)(idx / NC);
      labelA[b*TOPN+r] = (int)(idx % NC);
    }
  }
}

__global__ void k5_kmat(const float* __restrict__ k0p, const float* __restrict__ k1p,
                        const float* __restrict__ k2p, const float* __restrict__ k3p,
                        const float* __restrict__ k4p,
                        const int* __restrict__ cellA, float* __restrict__ Kmat){
  int t = blockIdx.x*blockDim.x + threadIdx.x;
  if (t >= NBATCH*TOPN*CHN) return;
  int b = t / (TOPN*CHN); int rem = t - b*(TOPN*CHN);
  int k = rem / CHN; int c = rem - k*CHN;
  int cell = cellA[b*TOPN + k];
  int lvl,g,y,x; cell_decode(cell,lvl,g,y,x);
  const float* kp = lvl==0?k0p:lvl==1?k1p:lvl==2?k2p:lvl==3?k3p:k4p;
  Kmat[t] = kp[((size_t)(b*CHN + c)*g + y)*g + x];
}

// 128x128 tile, 256 threads, 8x8 micro-tile; transposed-A LDS (all-b128 compute
// reads) + register prefetch of next K-tile during compute.
__global__ __launch_bounds__(256) void k6_gemm1(const float* __restrict__ Kmat, const float* __restrict__ mf,
        uint32_t* __restrict__ bits, float* __restrict__ psum, float* __restrict__ pseg){
  __shared__ alignas(16) float As[BK][BM+4];   // transposed: As[kk][row]
  __shared__ alignas(16) float Bs[BK][BN];
  __shared__ uint32_t bitsL[BM][4];
  int tid = threadIdx.x;
  int nb = blockIdx.x, mb = blockIdx.y, b = blockIdx.z;
  int row0 = mb*BM, col0 = nb*BN;
  int tx = tid & 15, ty = tid >> 4;
  for (int i = tid; i < BM*4; i += 256) ((uint32_t*)bitsL)[i] = 0;

  // per-thread staging coordinates (e = i*256 + tid)
  int ar[4], aq[4], bk_[4], bc[4];
  #pragma unroll
  for (int i = 0; i < 4; ++i) {
    int e = i*256 + tid;
    ar[i] = e >> 3; aq[i] = e & 7;      // A: 128 rows x 8 float4-of-k
    bk_[i] = e >> 5; bc[i] = e & 31;    // B: 32 kk x 32 float4-of-col
  }
  float4 pa0,pa1,pa2,pa3, pb0,pb1,pb2,pb3;
  const float4 z4 = make_float4(0.f,0.f,0.f,0.f);
  #define LOADA(i, dst) { int rr = row0 + ar[i]; \
    dst = (rr < TOPN) ? *(const float4*)&Kmat[((size_t)b*TOPN + rr)*CHN + k0n + aq[i]*4] : z4; }
  #define LOADB(i, dst) { dst = *(const float4*)&mf[((size_t)b*CHN + k0n + bk_[i])*HWN + col0 + bc[i]*4]; }
  {
    int k0n = 0;
    LOADA(0,pa0) LOADA(1,pa1) LOADA(2,pa2) LOADA(3,pa3)
    LOADB(0,pb0) LOADB(1,pb1) LOADB(2,pb2) LOADB(3,pb3)
  }

  float acc[8][8];
  #pragma unroll
  for (int i=0;i<8;i++)
    #pragma unroll
    for(int j=0;j<8;j++) acc[i][j]=0.f;

  for (int k0 = 0; k0 < CHN; k0 += BK) {
    __syncthreads();
    // store prefetched tile (A transposed: 4 scalar writes per float4)
    #define STA(i, src) { As[aq[i]*4+0][ar[i]] = src.x; As[aq[i]*4+1][ar[i]] = src.y; \
                          As[aq[i]*4+2][ar[i]] = src.z; As[aq[i]*4+3][ar[i]] = src.w; }
    STA(0,pa0) STA(1,pa1) STA(2,pa2) STA(3,pa3)
    *(float4*)&Bs[bk_[0]][bc[0]*4] = pb0;
    *(float4*)&Bs[bk_[1]][bc[1]*4] = pb1;
    *(float4*)&Bs[bk_[2]][bc[2]*4] = pb2;
    *(float4*)&Bs[bk_[3]][bc[3]*4] = pb3;
    __syncthreads();
    if (k0 + BK < CHN) {
      int k0n = k0 + BK;
      LOADA(0,pa0) LOADA(1,pa1) LOADA(2,pa2) LOADA(3,pa3)
      LOADB(0,pb0) LOADB(1,pb1) LOADB(2,pb2) LOADB(3,pb3)
    }
    #pragma unroll 4
    for (int kk = 0; kk < BK; ++kk) {
      float4 a0 = *(float4*)&As[kk][ty*8];
      float4 a1 = *(float4*)&As[kk][ty*8+4];
      float4 b0 = *(float4*)&Bs[kk][tx*4];
      float4 b1 = *(float4*)&Bs[kk][64+tx*4];
      float a[8] = {a0.x,a0.y,a0.z,a0.w,a1.x,a1.y,a1.z,a1.w};
      #pragma unroll
      for (int i = 0; i < 8; ++i) {
        acc[i][0] += a[i]*b0.x; acc[i][1] += a[i]*b0.y; acc[i][2] += a[i]*b0.z; acc[i][3] += a[i]*b0.w;
        acc[i][4] += a[i]*b1.x; acc[i][5] += a[i]*b1.y; acc[i][6] += a[i]*b1.z; acc[i][7] += a[i]*b1.w;
      }
    }
  }
  // epilogue: sigmoid, bit-pack, per-row count & seg-sum
  int w1 = tx >> 3;
  int sh = (tx*4) & 31;
  #pragma unroll
  for (int i = 0; i < 8; ++i) {
    int r = row0 + ty*8 + i;
    uint32_t mb1 = 0, mb2 = 0; float seg = 0.f; int cc = 0;
    #pragma unroll
    for (int j = 0; j < 4; ++j) {
      float s0 = sigmoidf_(acc[i][j]);
      float s1 = sigmoidf_(acc[i][4+j]);
      if (s0 > 0.5f) { mb1 |= (1u << j); seg += s0; cc++; }
      if (s1 > 0.5f) { mb2 |= (1u << j); seg += s1; cc++; }
    }
    if (r < TOPN) {
      atomicOr(&bitsL[ty*8+i][w1],     mb1 << sh);
      atomicOr(&bitsL[ty*8+i][2+w1],   mb2 << sh);
    }
    #pragma unroll
    for (int d = 1; d < 16; d <<= 1) {
      seg += __shfl_xor(seg, d);
      cc  += __shfl_xor(cc, d);
    }
    if (tx == 0 && r < TOPN) {
      psum[((size_t)b*TOPN + r)*GNB + nb] = (float)cc;
      pseg[((size_t)b*TOPN + r)*GNB + nb] = seg;
    }
  }
  __syncthreads();
  for (int e = tid; e < BM*4; e += 256) {
    int rr = e >> 2, w = e & 3;
    if (row0 + rr < TOPN)
      bits[((size_t)b*TOPN + row0 + rr)*512 + (col0>>5) + w] = bitsL[rr][w];
  }
}

__global__ void k7_rowstats(const float* __restrict__ psum, const float* __restrict__ pseg,
                            const float* __restrict__ vals, const int* __restrict__ cellA,
                            float* __restrict__ summ, float* __restrict__ scores, int* __restrict__ keepA){
  int t = blockIdx.x*blockDim.x + threadIdx.x;
  if (t >= NBATCH*TOPN) return;
  float sc = 0.f, sg = 0.f;
  for (int i = 0; i < GNB; i += 4) {
    float4 a = *(const float4*)&psum[(size_t)t*GNB+i];
    float4 c = *(const float4*)&pseg[(size_t)t*GNB+i];
    sc += a.x+a.y+a.z+a.w; sg += c.x+c.y+c.z+c.w;
  }
  float v = vals[t];
  int cell = cellA[t];
  int lvl,g,y,x; cell_decode(cell,lvl,g,y,x);
  float stride = (lvl<=1)?8.f:(lvl==2)?16.f:32.f;
  bool keep = (v > 0.1f) && (sc > stride);
  float seg = sg / fmaxf(sc, 1e-6f);
  summ[t] = sc;
  scores[t] = keep ? v*seg : 0.f;
  keepA[t] = keep ? 1 : 0;
}

__global__ __launch_bounds__(512) void k8_order(const float* __restrict__ scores, int* __restrict__ order){
  __shared__ uint64_t key[512];
  int b = blockIdx.x, tid = threadIdx.x;
  uint64_t k = 0;
  if (tid < TOPN)
    k = ((uint64_t)__float_as_uint(scores[b*TOPN+tid]) << 32) | (uint64_t)(0xFFFFFFFFu - (uint32_t)tid);
  key[tid] = k;
  bitonic_desc<512,512>(key);
  if (tid < TOPN) order[b*TOPN+tid] = (int)(0xFFFFFFFFu - (uint32_t)(key[tid] & 0xFFFFFFFFu));
}

__global__ __launch_bounds__(256) void k9_dmat(const uint32_t* __restrict__ bitsG,
        const int* __restrict__ order, const int* __restrict__ labelA, const int* __restrict__ keepA,
        const float* __restrict__ summ, float* __restrict__ dmat){
  __shared__ uint32_t rowb[512];
  __shared__ int labL[TOPN];
  __shared__ int ojL[TOPN];
  __shared__ int redI[4];
  int i = blockIdx.x, b = blockIdx.y, tid = threadIdx.x;
  float* drow = dmat + ((size_t)b*TOPN + i)*TOPN;
  for (int j = tid; j < TOPN; j += 256) drow[j] = 0.f;
  int oi = order[b*TOPN + i];
  int ki = keepA[b*TOPN + oi];
  if (!ki) return;                 // uniform across block
  float si = summ[b*TOPN + oi];
  for (int w = tid; w < 512; w += 256) rowb[w] = bitsG[((size_t)b*TOPN + oi)*512 + w];
  for (int j = tid; j < TOPN; j += 256) {
    int oj = order[b*TOPN + j];
    ojL[j] = oj;
    labL[j] = keepA[b*TOPN + oj] ? labelA[b*TOPN + oj] : -1;
  }
  __syncthreads();
  int li = labL[i];
  for (int j = i+1; j < TOPN; ++j) {
    if (labL[j] != li) continue;
    int oj = ojL[j];
    int cc = 0;
    for (int w = tid; w < 512; w += 256)
      cc += __popc(rowb[w] & bitsG[((size_t)b*TOPN + oj)*512 + w]);
    #pragma unroll
    for (int d = 1; d < 64; d <<= 1) cc += __shfl_xor(cc, d);
    if ((tid & 63) == 0) redI[tid >> 6] = cc;
    __syncthreads();
    if (tid == 0) {
      float inter = (float)(redI[0]+redI[1]+redI[2]+redI[3]);
      float sj = summ[b*TOPN + oj];
      drow[j] = inter / fmaxf(si + sj - inter, 1e-6f);
    }
    __syncthreads();
  }
}

__global__ __launch_bounds__(256) void k10_comp(const float* __restrict__ dmat,
        float* __restrict__ comp, float* __restrict__ e2c){
  __shared__ float red[4];
  int j = blockIdx.x, b = blockIdx.y, tid = threadIdx.x;
  float m = 0.f;
  for (int i = tid; i < TOPN; i += 256) m = fmaxf(m, dmat[((size_t)b*TOPN+i)*TOPN + j]);
  #pragma unroll
  for (int d = 1; d < 64; d <<= 1) m = fmaxf(m, __shfl_xor(m, d));
  if ((tid & 63) == 0) red[tid >> 6] = m;
  __syncthreads();
  if (tid == 0) {
    m = fmaxf(fmaxf(red[0], red[1]), fmaxf(red[2], red[3]));
    comp[b*TOPN+j] = m;
    e2c[b*TOPN+j] = expf(-2.0f*m*m);
  }
}

__global__ __launch_bounds__(256) void k10_coef(const float* __restrict__ dmat, const float* __restrict__ e2c,
        const float* __restrict__ scores, const int* __restrict__ order, const int* __restrict__ keepA,
        float* __restrict__ s2){
  __shared__ float red[4];
  int j = blockIdx.x, b = blockIdx.y, tid = threadIdx.x;
  float mn = 1e30f;
  for (int i = tid; i < TOPN; i += 256) {
    float d = dmat[((size_t)b*TOPN+i)*TOPN + j];
    float r = expf(-2.0f*d*d) / e2c[b*TOPN+i];
    mn = fminf(mn, r);
  }
  #pragma unroll
  for (int d = 1; d < 64; d <<= 1) mn = fminf(mn, __shfl_xor(mn, d));
  if ((tid & 63) == 0) red[tid >> 6] = mn;
  __syncthreads();
  if (tid == 0) {
    mn = fminf(fminf(red[0], red[1]), fminf(red[2], red[3]));
    int oj = order[b*TOPN+j];
    float s = scores[b*TOPN+oj] * mn;
    bool ok = (s >= 0.05f) && (s >= 0.1f) && (keepA[b*TOPN+oj] != 0);
    s2[b*TOPN+j] = ok ? s : 0.f;
  }
}

__global__ __launch_bounds__(512) void k11_top100(const float* __restrict__ s2, const int* __restrict__ order,
        const int* __restrict__ labelA, float* __restrict__ outF, int* __restrict__ selrow){
  __shared__ uint64_t key[512];
  int b = blockIdx.x, tid = threadIdx.x;
  uint64_t k = 0;
  if (tid < TOPN)
    k = ((uint64_t)__float_as_uint(s2[b*TOPN+tid]) << 32) | (uint64_t)(0xFFFFFFFFu - (uint32_t)tid);
  key[tid] = k;
  bitonic_desc<512,512>(key);
  if (tid < MAXM) {
    uint64_t kk = key[tid];
    float v = __uint_as_float((uint32_t)(kk >> 32));
    int j = (int)(0xFFFFFFFFu - (uint32_t)(kk & 0xFFFFFFFFu));
    if (j < 0 || j >= TOPN) { j = 0; v = 0.f; }
    int orow = order[b*TOPN + j];
    float lab = (v > 0.f) ? (float)labelA[b*TOPN + orow] : -1.0f;
    size_t maskCount = (size_t)NBATCH*MAXM*OUTH*OUTW;
    outF[maskCount + (size_t)b*MAXM + tid] = lab;
    outF[maskCount + (size_t)NBATCH*MAXM + (size_t)b*MAXM + tid] = v;
    selrow[b*MAXM + tid] = orow;
  }
}

__global__ __launch_bounds__(256) void k12_gemm2(const float* __restrict__ Kmat, const float* __restrict__ mf,
        const int* __restrict__ selrow, float* __restrict__ sigsel){
  __shared__ alignas(16) float As[BK][BM+4];
  __shared__ alignas(16) float Bs[BK][BN];
  __shared__ int selL[BM];
  int tid = threadIdx.x;
  int nb = blockIdx.x, b = blockIdx.z;
  int col0 = nb*BN;
  int tx = tid & 15, ty = tid >> 4;
  if (tid < BM) selL[tid] = (tid < MAXM) ? selrow[b*MAXM + tid] : 0;
  __syncthreads();

  int ar[4], aq[4], bk_[4], bc[4];
  #pragma unroll
  for (int i = 0; i < 4; ++i) {
    int e = i*256 + tid;
    ar[i] = e >> 3; aq[i] = e & 7;
    bk_[i] = e >> 5; bc[i] = e & 31;
  }
  float4 pa0,pa1,pa2,pa3, pb0,pb1,pb2,pb3;
  const float4 z4 = make_float4(0.f,0.f,0.f,0.f);
  #define LOADA2(i, dst) { int rr = ar[i]; \
    dst = (rr < MAXM) ? *(const float4*)&Kmat[((size_t)b*TOPN + selL[rr])*CHN + k0n + aq[i]*4] : z4; }
  {
    int k0n = 0;
    LOADA2(0,pa0) LOADA2(1,pa1) LOADA2(2,pa2) LOADA2(3,pa3)
    LOADB(0,pb0) LOADB(1,pb1) LOADB(2,pb2) LOADB(3,pb3)
  }
  float acc[8][8];
  #pragma unroll
  for (int i=0;i<8;i++)
    #pragma unroll
    for(int j=0;j<8;j++) acc[i][j]=0.f;

  for (int k0 = 0; k0 < CHN; k0 += BK) {
    __syncthreads();
    STA(0,pa0) STA(1,pa1) STA(2,pa2) STA(3,pa3)
    *(float4*)&Bs[bk_[0]][bc[0]*4] = pb0;
    *(float4*)&Bs[bk_[1]][bc[1]*4] = pb1;
    *(float4*)&Bs[bk_[2]][bc[2]*4] = pb2;
    *(float4*)&Bs[bk_[3]][bc[3]*4] = pb3;
    __syncthreads();
    if (k0 + BK < CHN) {
      int k0n = k0 + BK;
      LOADA2(0,pa0) LOADA2(1,pa1) LOADA2(2,pa2) LOADA2(3,pa3)
      LOADB(0,pb0) LOADB(1,pb1) LOADB(2,pb2) LOADB(3,pb3)
    }
    #pragma unroll 4
    for (int kk = 0; kk < BK; ++kk) {
      float4 a0 = *(float4*)&As[kk][ty*8];
      float4 a1 = *(float4*)&As[kk][ty*8+4];
      float4 b0 = *(float4*)&Bs[kk][tx*4];
      float4 b1 = *(float4*)&Bs[kk][64+tx*4];
      float a[8] = {a0.x,a0.y,a0.z,a0.w,a1.x,a1.y,a1.z,a1.w};
      #pragma unroll
      for (int i = 0; i < 8; ++i) {
        acc[i][0] += a[i]*b0.x; acc[i][1] += a[i]*b0.y; acc[i][2] += a[i]*b0.z; acc[i][3] += a[i]*b0.w;
        acc[i][4] += a[i]*b1.x; acc[i][5] += a[i]*b1.y; acc[i][6] += a[i]*b1.z; acc[i][7] += a[i]*b1.w;
      }
    }
  }
  #pragma unroll
  for (int i = 0; i < 8; ++i) {
    int r = ty*8 + i;
    if (r < MAXM) {
      float4 s0 = make_float4(sigmoidf_(acc[i][0]), sigmoidf_(acc[i][1]), sigmoidf_(acc[i][2]), sigmoidf_(acc[i][3]));
      float4 s1 = make_float4(sigmoidf_(acc[i][4]), sigmoidf_(acc[i][5]), sigmoidf_(acc[i][6]), sigmoidf_(acc[i][7]));
      size_t base = ((size_t)b*MAXM + r)*HWN + col0;
      *(float4*)&sigsel[base + tx*4]      = s0;
      *(float4*)&sigsel[base + 64 + tx*4] = s1;
    }
  }
}

__global__ void k13_upsample(const float* __restrict__ sigsel, float* __restrict__ outF){
  int t = blockIdx.x*blockDim.x + threadIdx.x;
  const int XG = OUTW/4;
  int total = NBATCH*MAXM*OUTH*XG;
  if (t >= total) return;
  int xg = t % XG;
  int tmp = t / XG;
  int Y = tmp % OUTH;
  int tmp2 = tmp / OUTH;
  int r = tmp2 % MAXM;
  int b = tmp2 / MAXM;
  size_t maskCount = (size_t)NBATCH*MAXM*OUTH*OUTW;
  float fv = outF[maskCount + (size_t)NBATCH*MAXM + (size_t)b*MAXM + r];
  float4 o = make_float4(0.f,0.f,0.f,0.f);
  if (fv > 0.f) {
    const float* sm = sigsel + ((size_t)b*MAXM + r)*HWN;
    const float SC = (float)(127.0/511.0);
    float fy = (float)Y * SC;
    int ly = (int)floorf(fy); if (ly < 0) ly = 0; if (ly > HMM-1) ly = HMM-1;
    int hy = ly+1 < HMM ? ly+1 : HMM-1;
    float wy = fy - (float)ly;
    float res[4];
    #pragma unroll
    for (int u = 0; u < 4; ++u) {
      int X = xg*4 + u;
      float fx = (float)X * SC;
      int lx = (int)floorf(fx); if (lx < 0) lx = 0; if (lx > HMM-1) lx = HMM-1;
      int hx = lx+1 < HMM ? lx+1 : HMM-1;
      float wx = fx - (float)lx;
      float a = (1.f-wy)*sm[ly*HMM+lx] + wy*sm[hy*HMM+lx];
      float c = (1.f-wy)*sm[ly*HMM+hx] + wy*sm[hy*HMM+hx];
      float v = (1.f-wx)*a + wx*c;
      res[u] = (v > 0.5f) ? 1.f : 0.f;
    }
    o = make_float4(res[0],res[1],res[2],res[3]);
  }
  *(float4*)&outF[(((size_t)b*MAXM + r)*OUTH + Y)*OUTW + xg*4] = o;
}

extern "C" void kernel_launch(void* const* d_in, const int* in_sizes, int n_in,
                              void* d_out, int out_size, void* d_ws, size_t ws_size,
                              hipStream_t stream) {
  const float* mf = (const float*)d_in[0];
  const float *cate[5], *kern[5];
  bool interleaved = (n_in > 2) && (in_sizes[2] == NBATCH*CHN*40*40);
  if (interleaved) {
    for (int i = 0; i < 5; ++i) { cate[i] = (const float*)d_in[1 + 2*i]; kern[i] = (const float*)d_in[2 + 2*i]; }
  } else {
    for (int i = 0; i < 5; ++i) { cate[i] = (const float*)d_in[1 + i]; kern[i] = (const float*)d_in[6 + i]; }
  }
  float* outF = (float*)d_out;

  uint8_t* p = (uint8_t*)d_ws;
  auto alloc = [&](size_t bytes) -> void* {
    void* r = (void*)p;
    p += (bytes + 255) & ~(size_t)255;
    return r;
  };
  float*    cate_scores = (float*)   alloc((size_t)NBATCH*FLATN*4);
  uint32_t* hist        = (uint32_t*)alloc((size_t)NBATCH*NBINS*4);
  uint32_t* cnt         = (uint32_t*)alloc((size_t)NBATCH*4);
  int*      cutoff      = (int*)     alloc((size_t)NBATCH*4);
  float*    cval        = (float*)   alloc((size_t)NBATCH*CANDCAP*4);
  uint32_t* cidx        = (uint32_t*)alloc((size_t)NBATCH*CANDCAP*4);
  float*    vals        = (float*)   alloc((size_t)NBATCH*TOPN*4);
  int*      cellA       = (int*)     alloc((size_t)NBATCH*TOPN*4);
  int*      labelA      = (int*)     alloc((size_t)NBATCH*TOPN*4);
  float*    Kmat        = (float*)   alloc((size_t)NBATCH*TOPN*CHN*4);
  uint32_t* bits        = (uint32_t*)alloc((size_t)NBATCH*TOPN*512*4);
  float*    psum        = (float*)   alloc((size_t)NBATCH*TOPN*GNB*4);
  float*    pseg        = (float*)   alloc((size_t)NBATCH*TOPN*GNB*4);
  float*    summ        = (float*)   alloc((size_t)NBATCH*TOPN*4);
  float*    scores      = (float*)   alloc((size_t)NBATCH*TOPN*4);
  int*      keepA       = (int*)     alloc((size_t)NBATCH*TOPN*4);
  int*      order       = (int*)     alloc((size_t)NBATCH*TOPN*4);
  float*    dmat        = (float*)   alloc((size_t)NBATCH*TOPN*TOPN*4);
  float*    comp        = (float*)   alloc((size_t)NBATCH*TOPN*4);
  float*    e2c         = (float*)   alloc((size_t)NBATCH*TOPN*4);
  float*    s2          = (float*)   alloc((size_t)NBATCH*TOPN*4);
  int*      selrow      = (int*)     alloc((size_t)NBATCH*MAXM*4);
  float*    sigsel      = (float*)   alloc((size_t)NBATCH*MAXM*HWN*4);
  (void)ws_size; (void)out_size;

  hipLaunchKernelGGL(k0_init, dim3((NBATCH*NBINS + 255)/256), dim3(256), 0, stream, hist, cnt);
  hipLaunchKernelGGL(k1_scores, dim3((NBATCH*FLATN + 255)/256), dim3(256), 0, stream,
                     cate[0], cate[1], cate[2], cate[3], cate[4], cate_scores, hist);
  hipLaunchKernelGGL(k2_cutoff, dim3(NBATCH), dim3(1024), 0, stream, hist, cutoff);
  hipLaunchKernelGGL(k3_gather, dim3((NBATCH*FLATN + 255)/256), dim3(256), 0, stream,
                     cate_scores, cutoff, cnt, cval, cidx);
  hipLaunchKernelGGL(k4_sort, dim3(NBATCH), dim3(1024), 0, stream, cnt, cval, cidx, vals, cellA, labelA);
  hipLaunchKernelGGL(k5_kmat, dim3((NBATCH*TOPN*CHN + 255)/256), dim3(256), 0, stream,
                     kern[0], kern[1], kern[2], kern[3], kern[4], cellA, Kmat);
  hipLaunchKernelGGL(k6_gemm1, dim3(GNB, (TOPN+BM-1)/BM, NBATCH), dim3(256), 0, stream,
                     Kmat, mf, bits, psum, pseg);
  hipLaunchKernelGGL(k7_rowstats, dim3((NBATCH*TOPN + 255)/256), dim3(256), 0, stream,
                     psum, pseg, vals, cellA, summ, scores, keepA);
  hipLaunchKernelGGL(k8_order, dim3(NBATCH), dim3(512), 0, stream, scores, order);
  hipLaunchKernelGGL(k9_dmat, dim3(TOPN, NBATCH), dim3(256), 0, stream,
                     bits, order, labelA, keepA, summ, dmat);
  hipLaunchKernelGGL(k10_comp, dim3(TOPN, NBATCH), dim3(256), 0, stream, dmat, comp, e2c);
  hipLaunchKernelGGL(k10_coef, dim3(TOPN, NBATCH), dim3(256), 0, stream,
                     dmat, e2c, scores, order, keepA, s2);
  hipLaunchKernelGGL(k11_top100, dim3(NBATCH), dim3(512), 0, stream, s2, order, labelA, outF, selrow);
  hipLaunchKernelGGL(k12_gemm2, dim3(GNB, 1, NBATCH), dim3(256), 0, stream,
                     Kmat, mf, selrow, sigsel);
  hipLaunchKernelGGL(k13_upsample, dim3((NBATCH*MAXM*OUTH*(OUTW/4) + 255)/256), dim3(256), 0, stream,
                     sigsel, outF);
}

// Round 4
// 390.284 us; speedup vs baseline: 1.8173x; 1.1727x over previous
//
#include <hip/hip_runtime.h>
#include <math.h>
#include <stdint.h>

#define NBATCH 2
#define NC 80
#define CHN 256
#define HMM 128
#define HWN (HMM*HMM)
#define NCELL 3872
#define FLATN (NCELL*NC)
#define TOPN 500
#define SROWS 512
#define MAXM 100
#define OUTH 512
#define OUTW 512
#define NBINS 1024
#define CANDCAP 2048
#define BM 128
#define BN2 256
#define BK 32
#define GNB (HWN/BN2)   // 64 N-blocks per row

__device__ __forceinline__ float sigmoidf_(float x){ return 1.0f/(1.0f+expf(-x)); }

__device__ __forceinline__ void cell_decode(int cell, int& lvl, int& g, int& y, int& x){
  int off;
  if (cell < 1600)      { lvl=0; g=40; off=0; }
  else if (cell < 2896) { lvl=1; g=36; off=1600; }
  else if (cell < 3472) { lvl=2; g=24; off=2896; }
  else if (cell < 3728) { lvl=3; g=16; off=3472; }
  else                  { lvl=4; g=12; off=3728; }
  int r = cell - off; y = r / g; x = r - y*g;
}

template<int N, int NT>
__device__ __forceinline__ void bitonic_desc(uint64_t* key){
  int tid = threadIdx.x;
  for (int k = 2; k <= N; k <<= 1)
    for (int j = k >> 1; j > 0; j >>= 1) {
      __syncthreads();
      for (int e = tid; e < N; e += NT) {
        int l = e ^ j;
        if (l > e) {
          uint64_t a = key[e], c = key[l];
          bool up = ((e & k) == 0);
          if (up ? (a < c) : (a > c)) { key[e] = c; key[l] = a; }
        }
      }
    }
  __syncthreads();
}

__global__ void k0_init(uint32_t* hist, uint32_t* cnt){
  int t = blockIdx.x*blockDim.x + threadIdx.x;
  if (t < NBATCH*NBINS) hist[t] = 0;
  if (t < NBATCH) cnt[t] = 0;
}

__global__ void k1_scores(const float* __restrict__ c0, const float* __restrict__ c1,
                          const float* __restrict__ c2, const float* __restrict__ c3,
                          const float* __restrict__ c4,
                          float* __restrict__ scores, uint32_t* __restrict__ hist){
  int t = blockIdx.x*blockDim.x + threadIdx.x;
  if (t >= NBATCH*FLATN) return;
  int b = t / FLATN;
  int rem = t - b*FLATN;
  int cell = rem / NC;
  int c = rem - cell*NC;
  int lvl,g,y,x; cell_decode(cell,lvl,g,y,x);
  const float* cp = lvl==0?c0:lvl==1?c1:lvl==2?c2:lvl==3?c3:c4;
  const float* base = cp + (size_t)(b*NC + c)*g*g;
  float raw = base[y*g + x];
  float m = raw;
  if (y > 0)          m = fmaxf(m, base[(y-1)*g + x]);
  if (x > 0)          m = fmaxf(m, base[y*g + x-1]);
  if (y > 0 && x > 0) m = fmaxf(m, base[(y-1)*g + x-1]);
  float s = (raw == m) ? sigmoidf_(raw) : 0.0f;
  scores[t] = s;
  if (s > 0.1f) {
    int bin = (int)(s * 1024.0f); if (bin > NBINS-1) bin = NBINS-1;
    atomicAdd(&hist[b*NBINS + bin], 1u);
  }
}

__global__ __launch_bounds__(1024) void k2_cutoff(const uint32_t* __restrict__ hist, int* __restrict__ cutoff){
  __shared__ uint32_t h[NBINS];
  int b = blockIdx.x;
  h[threadIdx.x] = hist[b*NBINS + threadIdx.x];
  __syncthreads();
  if (threadIdx.x == 0) {
    int acc = 0; int cut = 0;
    for (int d = NBINS-1; d >= 0; --d) {
      acc += (int)h[d];
      if (acc >= TOPN) { cut = d; break; }
    }
    cutoff[b] = cut;
  }
}

__global__ void k3_gather(const float* __restrict__ scores, const int* __restrict__ cutoff,
                          uint32_t* __restrict__ cnt, float* __restrict__ cval, uint32_t* __restrict__ cidx){
  int t = blockIdx.x*blockDim.x + threadIdx.x;
  if (t >= NBATCH*FLATN) return;
  int b = t / FLATN; int idx = t - b*FLATN;
  float v = scores[t];
  if (v > 0.1f) {
    int bin = (int)(v * 1024.0f); if (bin > NBINS-1) bin = NBINS-1;
    if (bin >= cutoff[b]) {
      uint32_t p = atomicAdd(&cnt[b], 1u);
      if (p < CANDCAP) { cval[b*CANDCAP+p] = v; cidx[b*CANDCAP+p] = (uint32_t)idx; }
    }
  }
}

__global__ __launch_bounds__(1024) void k4_sort(const uint32_t* __restrict__ cnt,
        const float* __restrict__ cval, const uint32_t* __restrict__ cidx,
        float* __restrict__ vals, int* __restrict__ cellA, int* __restrict__ labelA){
  __shared__ uint64_t key[CANDCAP];
  int b = blockIdx.x; int tid = threadIdx.x;
  int n = (int)cnt[b]; if (n > CANDCAP) n = CANDCAP;
  for (int e = tid; e < CANDCAP; e += 1024) {
    uint64_t k = 0;
    if (e < n)
      k = ((uint64_t)__float_as_uint(cval[b*CANDCAP+e]) << 32) |
          (uint64_t)(0xFFFFFFFFu - cidx[b*CANDCAP+e]);
    key[e] = k;
  }
  bitonic_desc<CANDCAP,1024>(key);
  for (int r = tid; r < TOPN; r += 1024) {
    uint64_t k = key[r];
    if ((k >> 32) == 0) { vals[b*TOPN+r] = -1.0f; cellA[b*TOPN+r] = 0; labelA[b*TOPN+r] = 0; }
    else {
      uint32_t idx = 0xFFFFFFFFu - (uint32_t)(k & 0xFFFFFFFFu);
      vals[b*TOPN+r]   = __uint_as_float((uint32_t)(k >> 32));
      cellA[b*TOPN+r]  = (int)(idx / NC);
      labelA[b*TOPN+r] = (int)(idx % NC);
    }
  }
}

__global__ void k5_kmat(const float* __restrict__ k0p, const float* __restrict__ k1p,
                        const float* __restrict__ k2p, const float* __restrict__ k3p,
                        const float* __restrict__ k4p,
                        const int* __restrict__ cellA, float* __restrict__ Kmat){
  int t = blockIdx.x*blockDim.x + threadIdx.x;
  if (t >= NBATCH*TOPN*CHN) return;
  int b = t / (TOPN*CHN); int rem = t - b*(TOPN*CHN);
  int k = rem / CHN; int c = rem - k*CHN;
  int cell = cellA[b*TOPN + k];
  int lvl,g,y,x; cell_decode(cell,lvl,g,y,x);
  const float* kp = lvl==0?k0p:lvl==1?k1p:lvl==2?k2p:lvl==3?k3p:k4p;
  Kmat[t] = kp[((size_t)(b*CHN + c)*g + y)*g + x];
}

// 128x256 tile, 256 threads, 8x16 micro-tile; XOR-swizzled transposed-A LDS,
// register prefetch, full sigmoid matrix written out (replaces gemm2).
__global__ __launch_bounds__(256, 2) void k6_gemm1(const float* __restrict__ Kmat, const float* __restrict__ mf,
        float* __restrict__ sigfull, uint32_t* __restrict__ bits,
        float* __restrict__ psum, float* __restrict__ pseg){
  __shared__ alignas(16) float As[BK][BM+4];   // transposed + swizzled: As[kk][row ^ ((kk>>2)<<2)]
  __shared__ alignas(16) float Bs[BK][BN2];
  __shared__ uint32_t bitsL[BM][8];
  int tid = threadIdx.x;
  int nb = blockIdx.x, mb = blockIdx.y, b = blockIdx.z;
  int row0 = mb*BM, col0 = nb*BN2;
  int tx = tid & 15, ty = tid >> 4;
  for (int i = tid; i < BM*8; i += 256) ((uint32_t*)bitsL)[i] = 0;

  int ar[4], aq[4], bkk[8], bcc[8];
  #pragma unroll
  for (int i = 0; i < 4; ++i) { int e = i*256 + tid; ar[i] = e >> 3; aq[i] = e & 7; }
  #pragma unroll
  for (int i = 0; i < 8; ++i) { int e = i*256 + tid; bkk[i] = e >> 6; bcc[i] = e & 63; }

  float4 pa[4], pb[8];
  const float4 z4 = make_float4(0.f,0.f,0.f,0.f);
  #pragma unroll
  for (int i = 0; i < 4; ++i) {
    int rr = row0 + ar[i];
    pa[i] = (rr < TOPN) ? *(const float4*)&Kmat[((size_t)b*TOPN + rr)*CHN + aq[i]*4] : z4;
  }
  #pragma unroll
  for (int i = 0; i < 8; ++i)
    pb[i] = *(const float4*)&mf[((size_t)b*CHN + bkk[i])*HWN + col0 + bcc[i]*4];

  float acc[8][16];
  #pragma unroll
  for (int i=0;i<8;i++)
    #pragma unroll
    for(int j=0;j<16;j++) acc[i][j]=0.f;

  for (int k0 = 0; k0 < CHN; k0 += BK) {
    __syncthreads();
    #pragma unroll
    for (int i = 0; i < 4; ++i) {
      int colA = ar[i] ^ (aq[i] << 2);
      As[aq[i]*4+0][colA] = pa[i].x;
      As[aq[i]*4+1][colA] = pa[i].y;
      As[aq[i]*4+2][colA] = pa[i].z;
      As[aq[i]*4+3][colA] = pa[i].w;
    }
    #pragma unroll
    for (int i = 0; i < 8; ++i)
      *(float4*)&Bs[bkk[i]][bcc[i]*4] = pb[i];
    __syncthreads();
    if (k0 + BK < CHN) {
      int k0n = k0 + BK;
      #pragma unroll
      for (int i = 0; i < 4; ++i) {
        int rr = row0 + ar[i];
        pa[i] = (rr < TOPN) ? *(const float4*)&Kmat[((size_t)b*TOPN + rr)*CHN + k0n + aq[i]*4] : z4;
      }
      #pragma unroll
      for (int i = 0; i < 8; ++i)
        pb[i] = *(const float4*)&mf[((size_t)b*CHN + k0n + bkk[i])*HWN + col0 + bcc[i]*4];
    }
    #pragma unroll 2
    for (int kk = 0; kk < BK; ++kk) {
      int s = (kk >> 2) << 2;
      float4 a0 = *(float4*)&As[kk][(ty*8) ^ s];
      float4 a1 = *(float4*)&As[kk][(ty*8+4) ^ s];
      float av[8] = {a0.x,a0.y,a0.z,a0.w,a1.x,a1.y,a1.z,a1.w};
      #pragma unroll
      for (int q = 0; q < 4; ++q) {
        float4 bv = *(float4*)&Bs[kk][q*64 + tx*4];
        #pragma unroll
        for (int i = 0; i < 8; ++i) {
          acc[i][q*4+0] += av[i]*bv.x;
          acc[i][q*4+1] += av[i]*bv.y;
          acc[i][q*4+2] += av[i]*bv.z;
          acc[i][q*4+3] += av[i]*bv.w;
        }
      }
    }
  }
  // epilogue: sigmoid, store sig, bit-pack, per-row count & seg-sum
  #pragma unroll
  for (int i = 0; i < 8; ++i) {
    int r = row0 + ty*8 + i;
    float se = 0.f; int cc = 0;
    #pragma unroll
    for (int q = 0; q < 4; ++q) {
      float4 sv;
      sv.x = sigmoidf_(acc[i][q*4+0]);
      sv.y = sigmoidf_(acc[i][q*4+1]);
      sv.z = sigmoidf_(acc[i][q*4+2]);
      sv.w = sigmoidf_(acc[i][q*4+3]);
      uint32_t m = 0;
      if (sv.x > 0.5f) { m |= 1u; se += sv.x; cc++; }
      if (sv.y > 0.5f) { m |= 2u; se += sv.y; cc++; }
      if (sv.z > 0.5f) { m |= 4u; se += sv.z; cc++; }
      if (sv.w > 0.5f) { m |= 8u; se += sv.w; cc++; }
      atomicOr(&bitsL[ty*8+i][2*q + (tx>>3)], m << ((tx&7)*4));
      *(float4*)&sigfull[((size_t)b*SROWS + r)*HWN + col0 + q*64 + tx*4] = sv;
    }
    #pragma unroll
    for (int d = 1; d < 16; d <<= 1) {
      se += __shfl_xor(se, d);
      cc += __shfl_xor(cc, d);
    }
    if (tx == 0 && r < TOPN) {
      psum[((size_t)b*TOPN + r)*GNB + nb] = (float)cc;
      pseg[((size_t)b*TOPN + r)*GNB + nb] = se;
    }
  }
  __syncthreads();
  for (int e = tid; e < BM*8; e += 256) {
    int rr = e >> 3, w = e & 7;
    if (row0 + rr < TOPN)
      bits[((size_t)b*TOPN + row0 + rr)*512 + nb*8 + w] = bitsL[rr][w];
  }
}

__global__ void k7_rowstats(const float* __restrict__ psum, const float* __restrict__ pseg,
                            const float* __restrict__ vals, const int* __restrict__ cellA,
                            float* __restrict__ summ, float* __restrict__ scores, int* __restrict__ keepA){
  int t = blockIdx.x*blockDim.x + threadIdx.x;
  if (t >= NBATCH*TOPN) return;
  float sc = 0.f, sg = 0.f;
  for (int i = 0; i < GNB; i += 4) {
    float4 a = *(const float4*)&psum[(size_t)t*GNB+i];
    float4 c = *(const float4*)&pseg[(size_t)t*GNB+i];
    sc += a.x+a.y+a.z+a.w; sg += c.x+c.y+c.z+c.w;
  }
  float v = vals[t];
  int cell = cellA[t];
  int lvl,g,y,x; cell_decode(cell,lvl,g,y,x);
  float stride = (lvl<=1)?8.f:(lvl==2)?16.f:32.f;
  bool keep = (v > 0.1f) && (sc > stride);
  float seg = sg / fmaxf(sc, 1e-6f);
  summ[t] = sc;
  scores[t] = keep ? v*seg : 0.f;
  keepA[t] = keep ? 1 : 0;
}

__global__ __launch_bounds__(512) void k8_order(const float* __restrict__ scores, int* __restrict__ order){
  __shared__ uint64_t key[512];
  int b = blockIdx.x, tid = threadIdx.x;
  uint64_t k = 0;
  if (tid < TOPN)
    k = ((uint64_t)__float_as_uint(scores[b*TOPN+tid]) << 32) | (uint64_t)(0xFFFFFFFFu - (uint32_t)tid);
  key[tid] = k;
  bitonic_desc<512,512>(key);
  if (tid < TOPN) order[b*TOPN+tid] = (int)(0xFFFFFFFFu - (uint32_t)(key[tid] & 0xFFFFFFFFu));
}

// one block per (i,b); thread-per-j; writes TRANSPOSED dmatT[j][i] (only nonzero pairs)
__global__ __launch_bounds__(256) void k9_dmat(const uint32_t* __restrict__ bitsG,
        const int* __restrict__ order, const int* __restrict__ labelA, const int* __restrict__ keepA,
        const float* __restrict__ summ, float* __restrict__ dmatT){
  __shared__ uint32_t rowb[512];
  int i = blockIdx.x, b = blockIdx.y, tid = threadIdx.x;
  int oi = order[b*TOPN + i];
  if (!keepA[b*TOPN + oi]) return;
  float si = summ[b*TOPN + oi];
  int li = labelA[b*TOPN + oi];
  for (int w = tid; w < 512; w += 256) rowb[w] = bitsG[((size_t)b*TOPN + oi)*512 + w];
  __syncthreads();
  for (int j = i + 1 + tid; j < TOPN; j += 256) {
    int oj = order[b*TOPN + j];
    if (!keepA[b*TOPN + oj] || labelA[b*TOPN + oj] != li) continue;
    const uint4* rj = (const uint4*)&bitsG[((size_t)b*TOPN + oj)*512];
    const uint4* ri = (const uint4*)rowb;
    int cc = 0;
    for (int w = 0; w < 128; ++w) {
      uint4 x = rj[w], y = ri[w];
      cc += __popc(x.x & y.x) + __popc(x.y & y.y) + __popc(x.z & y.z) + __popc(x.w & y.w);
    }
    float sj = summ[b*TOPN + oj];
    float inter = (float)cc;
    dmatT[((size_t)b*TOPN + j)*TOPN + i] = inter / fmaxf(si + sj - inter, 1e-6f);
  }
}

__global__ __launch_bounds__(256) void k10_comp(const float* __restrict__ dmatT,
        float* __restrict__ comp, float* __restrict__ e2c){
  __shared__ float red[4];
  int j = blockIdx.x, b = blockIdx.y, tid = threadIdx.x;
  float m = 0.f;
  for (int i = tid; i < TOPN; i += 256) m = fmaxf(m, dmatT[((size_t)b*TOPN+j)*TOPN + i]);
  #pragma unroll
  for (int d = 1; d < 64; d <<= 1) m = fmaxf(m, __shfl_xor(m, d));
  if ((tid & 63) == 0) red[tid >> 6] = m;
  __syncthreads();
  if (tid == 0) {
    m = fmaxf(fmaxf(red[0], red[1]), fmaxf(red[2], red[3]));
    comp[b*TOPN+j] = m;
    e2c[b*TOPN+j] = expf(-2.0f*m*m);
  }
}

__global__ __launch_bounds__(256) void k10_coef(const float* __restrict__ dmatT, const float* __restrict__ e2c,
        const float* __restrict__ scores, const int* __restrict__ order, const int* __restrict__ keepA,
        float* __restrict__ s2){
  __shared__ float red[4];
  int j = blockIdx.x, b = blockIdx.y, tid = threadIdx.x;
  float mn = 1e30f;
  for (int i = tid; i < TOPN; i += 256) {
    float d = dmatT[((size_t)b*TOPN+j)*TOPN + i];
    float r = expf(-2.0f*d*d) / e2c[b*TOPN+i];
    mn = fminf(mn, r);
  }
  #pragma unroll
  for (int d = 1; d < 64; d <<= 1) mn = fminf(mn, __shfl_xor(mn, d));
  if ((tid & 63) == 0) red[tid >> 6] = mn;
  __syncthreads();
  if (tid == 0) {
    mn = fminf(fminf(red[0], red[1]), fminf(red[2], red[3]));
    int oj = order[b*TOPN+j];
    float s = scores[b*TOPN+oj] * mn;
    bool ok = (s >= 0.05f) && (s >= 0.1f) && (keepA[b*TOPN+oj] != 0);
    s2[b*TOPN+j] = ok ? s : 0.f;
  }
}

__global__ __launch_bounds__(512) void k11_top100(const float* __restrict__ s2, const int* __restrict__ order,
        const int* __restrict__ labelA, float* __restrict__ outF, int* __restrict__ selrow){
  __shared__ uint64_t key[512];
  int b = blockIdx.x, tid = threadIdx.x;
  uint64_t k = 0;
  if (tid < TOPN)
    k = ((uint64_t)__float_as_uint(s2[b*TOPN+tid]) << 32) | (uint64_t)(0xFFFFFFFFu - (uint32_t)tid);
  key[tid] = k;
  bitonic_desc<512,512>(key);
  if (tid < MAXM) {
    uint64_t kk = key[tid];
    float v = __uint_as_float((uint32_t)(kk >> 32));
    int j = (int)(0xFFFFFFFFu - (uint32_t)(kk & 0xFFFFFFFFu));
    if (j < 0 || j >= TOPN) { j = 0; v = 0.f; }
    int orow = order[b*TOPN + j];
    float lab = (v > 0.f) ? (float)labelA[b*TOPN + orow] : -1.0f;
    size_t maskCount = (size_t)NBATCH*MAXM*OUTH*OUTW;
    outF[maskCount + (size_t)b*MAXM + tid] = lab;
    outF[maskCount + (size_t)NBATCH*MAXM + (size_t)b*MAXM + tid] = v;
    selrow[b*MAXM + tid] = orow;
  }
}

__global__ void k13_upsample(const float* __restrict__ sigfull, const int* __restrict__ selrow,
                             float* __restrict__ outF){
  int t = blockIdx.x*blockDim.x + threadIdx.x;
  const int XG = OUTW/4;
  int total = NBATCH*MAXM*OUTH*XG;
  if (t >= total) return;
  int xg = t % XG;
  int tmp = t / XG;
  int Y = tmp % OUTH;
  int tmp2 = tmp / OUTH;
  int r = tmp2 % MAXM;
  int b = tmp2 / MAXM;
  size_t maskCount = (size_t)NBATCH*MAXM*OUTH*OUTW;
  float fv = outF[maskCount + (size_t)NBATCH*MAXM + (size_t)b*MAXM + r];
  float4 o = make_float4(0.f,0.f,0.f,0.f);
  if (fv > 0.f) {
    const float* sm = sigfull + ((size_t)b*SROWS + selrow[b*MAXM + r])*HWN;
    const float SC = (float)(127.0/511.0);
    float fy = (float)Y * SC;
    int ly = (int)floorf(fy); if (ly < 0) ly = 0; if (ly > HMM-1) ly = HMM-1;
    int hy = ly+1 < HMM ? ly+1 : HMM-1;
    float wy = fy - (float)ly;
    float res[4];
    #pragma unroll
    for (int u = 0; u < 4; ++u) {
      int X = xg*4 + u;
      float fx = (float)X * SC;
      int lx = (int)floorf(fx); if (lx < 0) lx = 0; if (lx > HMM-1) lx = HMM-1;
      int hx = lx+1 < HMM ? lx+1 : HMM-1;
      float wx = fx - (float)lx;
      float a = (1.f-wy)*sm[ly*HMM+lx] + wy*sm[hy*HMM+lx];
      float c = (1.f-wy)*sm[ly*HMM+hx] + wy*sm[hy*HMM+hx];
      float v = (1.f-wx)*a + wx*c;
      res[u] = (v > 0.5f) ? 1.f : 0.f;
    }
    o = make_float4(res[0],res[1],res[2],res[3]);
  }
  *(float4*)&outF[(((size_t)b*MAXM + r)*OUTH + Y)*OUTW + xg*4] = o;
}

extern "C" void kernel_launch(void* const* d_in, const int* in_sizes, int n_in,
                              void* d_out, int out_size, void* d_ws, size_t ws_size,
                              hipStream_t stream) {
  const float* mf = (const float*)d_in[0];
  const float *cate[5], *kern[5];
  bool interleaved = (n_in > 2) && (in_sizes[2] == NBATCH*CHN*40*40);
  if (interleaved) {
    for (int i = 0; i < 5; ++i) { cate[i] = (const float*)d_in[1 + 2*i]; kern[i] = (const float*)d_in[2 + 2*i]; }
  } else {
    for (int i = 0; i < 5; ++i) { cate[i] = (const float*)d_in[1 + i]; kern[i] = (const float*)d_in[6 + i]; }
  }
  float* outF = (float*)d_out;

  uint8_t* p = (uint8_t*)d_ws;
  auto alloc = [&](size_t bytes) -> void* {
    void* r = (void*)p;
    p += (bytes + 255) & ~(size_t)255;
    return r;
  };
  float*    cate_scores = (float*)   alloc((size_t)NBATCH*FLATN*4);
  uint32_t* hist        = (uint32_t*)alloc((size_t)NBATCH*NBINS*4);
  uint32_t* cnt         = (uint32_t*)alloc((size_t)NBATCH*4);
  int*      cutoff      = (int*)     alloc((size_t)NBATCH*4);
  float*    cval        = (float*)   alloc((size_t)NBATCH*CANDCAP*4);
  uint32_t* cidx        = (uint32_t*)alloc((size_t)NBATCH*CANDCAP*4);
  float*    vals        = (float*)   alloc((size_t)NBATCH*TOPN*4);
  int*      cellA       = (int*)     alloc((size_t)NBATCH*TOPN*4);
  int*      labelA      = (int*)     alloc((size_t)NBATCH*TOPN*4);
  float*    Kmat        = (float*)   alloc((size_t)NBATCH*TOPN*CHN*4);
  uint32_t* bits        = (uint32_t*)alloc((size_t)NBATCH*TOPN*512*4);
  float*    psum        = (float*)   alloc((size_t)NBATCH*TOPN*GNB*4);
  float*    pseg        = (float*)   alloc((size_t)NBATCH*TOPN*GNB*4);
  float*    summ        = (float*)   alloc((size_t)NBATCH*TOPN*4);
  float*    scores      = (float*)   alloc((size_t)NBATCH*TOPN*4);
  int*      keepA       = (int*)     alloc((size_t)NBATCH*TOPN*4);
  int*      order       = (int*)     alloc((size_t)NBATCH*TOPN*4);
  float*    dmatT       = (float*)   alloc((size_t)NBATCH*TOPN*TOPN*4);
  float*    comp        = (float*)   alloc((size_t)NBATCH*TOPN*4);
  float*    e2c         = (float*)   alloc((size_t)NBATCH*TOPN*4);
  float*    s2          = (float*)   alloc((size_t)NBATCH*TOPN*4);
  int*      selrow      = (int*)     alloc((size_t)NBATCH*MAXM*4);
  float*    sigfull     = (float*)   alloc((size_t)NBATCH*SROWS*HWN*4);
  (void)ws_size; (void)out_size;

  hipLaunchKernelGGL(k0_init, dim3((NBATCH*NBINS + 255)/256), dim3(256), 0, stream, hist, cnt);
  hipLaunchKernelGGL(k1_scores, dim3((NBATCH*FLATN + 255)/256), dim3(256), 0, stream,
                     cate[0], cate[1], cate[2], cate[3], cate[4], cate_scores, hist);
  hipLaunchKernelGGL(k2_cutoff, dim3(NBATCH), dim3(1024), 0, stream, hist, cutoff);
  hipLaunchKernelGGL(k3_gather, dim3((NBATCH*FLATN + 255)/256), dim3(256), 0, stream,
                     cate_scores, cutoff, cnt, cval, cidx);
  hipLaunchKernelGGL(k4_sort, dim3(NBATCH), dim3(1024), 0, stream, cnt, cval, cidx, vals, cellA, labelA);
  hipLaunchKernelGGL(k5_kmat, dim3((NBATCH*TOPN*CHN + 255)/256), dim3(256), 0, stream,
                     kern[0], kern[1], kern[2], kern[3], kern[4], cellA, Kmat);
  hipLaunchKernelGGL(k6_gemm1, dim3(HWN/BN2, (TOPN+BM-1)/BM, NBATCH), dim3(256), 0, stream,
                     Kmat, mf, sigfull, bits, psum, pseg);
  hipLaunchKernelGGL(k7_rowstats, dim3((NBATCH*TOPN + 255)/256), dim3(256), 0, stream,
                     psum, pseg, vals, cellA, summ, scores, keepA);
  hipLaunchKernelGGL(k8_order, dim3(NBATCH), dim3(512), 0, stream, scores, order);
  hipMemsetAsync(dmatT, 0, (size_t)NBATCH*TOPN*TOPN*4, stream);
  hipLaunchKernelGGL(k9_dmat, dim3(TOPN, NBATCH), dim3(256), 0, stream,
                     bits, order, labelA, keepA, summ, dmatT);
  hipLaunchKernelGGL(k10_comp, dim3(TOPN, NBATCH), dim3(256), 0, stream, dmatT, comp, e2c);
  hipLaunchKernelGGL(k10_coef, dim3(TOPN, NBATCH), dim3(256), 0, stream,
                     dmatT, e2c, scores, order, keepA, s2);
  hipLaunchKernelGGL(k11_top100, dim3(NBATCH), dim3(512), 0, stream, s2, order, labelA, outF, selrow);
  hipLaunchKernelGGL(k13_upsample, dim3((NBATCH*MAXM*OUTH*(OUTW/4) + 255)/256), dim3(256), 0, stream,
                     sigfull, selrow, outF);
}